// Round 13
// baseline (484.941 us; speedup 1.0000x reference)
//
#include <hip/hip_runtime.h>

// ---------------- constants ----------------
#define B_ 4
#define Hh_ 32
#define Ww_ 32
#define L_ 1024
#define HID_ 512
#define DI_ 1024
#define N_ 64
#define R_ 32
#define K_ 4
#define MLP_ 2048

typedef __bf16 bf16x8 __attribute__((ext_vector_type(8)));
typedef float f32x4 __attribute__((ext_vector_type(4)));
typedef float v2f __attribute__((ext_vector_type(2)));

__device__ __forceinline__ unsigned short f2bf(float f) {
  unsigned int u = __builtin_bit_cast(unsigned int, f);
  return (unsigned short)((u + 0x7FFFu + ((u >> 16) & 1u)) >> 16);
}
__device__ __forceinline__ float bf2f(unsigned short h) {
  return __builtin_bit_cast(float, (unsigned int)h << 16);
}
__device__ __forceinline__ v2f bfp2v(unsigned int u) {
  v2f r;
  r.x = __builtin_bit_cast(float, u << 16);
  r.y = __builtin_bit_cast(float, u & 0xFFFF0000u);
  return r;
}

// async global->LDS, 16B per lane; lds base must be wave-uniform
__device__ __forceinline__ void gload16(const unsigned short* g, unsigned short* l) {
  __builtin_amdgcn_global_load_lds(
      (const __attribute__((address_space(1))) unsigned int*)g,
      (__attribute__((address_space(3))) unsigned int*)l, 16, 0, 0);
}

// DPP add: x + x[perm(lane)] on the VALU pipe (no DS traffic)
template <int CTRL>
__device__ __forceinline__ float dpp_add(float x) {
  int i = __builtin_bit_cast(int, x);
  int j = __builtin_amdgcn_update_dpp(i, i, CTRL, 0xF, 0xF, false);
  return x + __builtin_bit_cast(float, j);
}

// ---------------- all 6 weight transposes in ONE launch ----------------
__global__ __launch_bounds__(256) void transpose_all(
    const float* __restrict__ s0, const float* __restrict__ s1,
    const float* __restrict__ s2, const float* __restrict__ s3,
    const float* __restrict__ s4, const float* __restrict__ s5,
    unsigned short* __restrict__ t0, unsigned short* __restrict__ t1,
    unsigned short* __restrict__ t2, unsigned short* __restrict__ t3,
    unsigned short* __restrict__ t4, unsigned short* __restrict__ t5) {
  __shared__ float t[32][33];
  int bid = blockIdx.x;
  const float* src; unsigned short* dst; int K, N, bx, by;
  if (bid < 1024)      { src = s0; dst = t0; K = 512;  N = 2048; int r = bid;        bx = r & 63; by = r >> 6; }
  else if (bid < 1216) { src = s1; dst = t1; K = 512;  N = 384;  int r = bid - 1024; bx = r % 12; by = r / 12; }
  else if (bid < 1472) { src = s2; dst = t2; K = 1024; N = 256;  int r = bid - 1216; bx = r & 7;  by = r >> 3; }
  else if (bid < 1984) { src = s3; dst = t3; K = 1024; N = 512;  int r = bid - 1472; bx = r & 15; by = r >> 4; }
  else if (bid < 3008) { src = s4; dst = t4; K = 512;  N = 2048; int r = bid - 1984; bx = r & 63; by = r >> 6; }
  else                 { src = s5; dst = t5; K = 2048; N = 512;  int r = bid - 3008; bx = r & 15; by = r >> 4; }
  int nb = bx * 32, kb = by * 32;
  int tx = threadIdx.x & 31, ty = threadIdx.x >> 5;
  for (int r = ty; r < 32; r += 8) t[r][tx] = src[(size_t)(kb + r) * N + nb + tx];
  __syncthreads();
  for (int r = ty; r < 32; r += 8) dst[(size_t)(nb + r) * K + kb + tx] = f2bf(t[tx][r]);
}

// ---------------- cast f32 -> bf16 (for dtw) ----------------
__global__ __launch_bounds__(256) void cast_bf(
    const float* __restrict__ src, unsigned short* __restrict__ dst) {
  int i = (blockIdx.x * 256 + threadIdx.x) * 4;
  float4 v = *(const float4*)(src + i);
  ushort4 o = {f2bf(v.x), f2bf(v.y), f2bf(v.z), f2bf(v.w)};
  *(ushort4*)(dst + i) = o;
}

// ---------------- LayerNorm over 512, wave per row; writes bf16 ----------------
__global__ __launch_bounds__(256) void ln_kernel(
    const float* __restrict__ in0, unsigned short* __restrict__ out0,
    const float* __restrict__ in1, unsigned short* __restrict__ out1,
    const float* __restrict__ w, const float* __restrict__ bb) {
  const float* in = blockIdx.y ? in1 : in0;
  unsigned short* out = blockIdx.y ? out1 : out0;
  int row = blockIdx.x * 4 + (threadIdx.x >> 6);
  int lane = threadIdx.x & 63;
  const float* p = in + (size_t)row * HID_;
  float4 v0 = *(const float4*)(p + lane * 4);
  float4 v1 = *(const float4*)(p + 256 + lane * 4);
  float s = v0.x + v0.y + v0.z + v0.w + v1.x + v1.y + v1.z + v1.w;
  float q = v0.x * v0.x + v0.y * v0.y + v0.z * v0.z + v0.w * v0.w +
            v1.x * v1.x + v1.y * v1.y + v1.z * v1.z + v1.w * v1.w;
  #pragma unroll
  for (int m = 1; m < 64; m <<= 1) { s += __shfl_xor(s, m, 64); q += __shfl_xor(q, m, 64); }
  float mean = s * (1.f / 512.f);
  float var = q * (1.f / 512.f) - mean * mean;
  float rstd = rsqrtf(var + 1e-5f);
  float4 w0 = *(const float4*)(w + lane * 4);
  float4 w1 = *(const float4*)(w + 256 + lane * 4);
  float4 b0 = *(const float4*)(bb + lane * 4);
  float4 b1 = *(const float4*)(bb + 256 + lane * 4);
  unsigned short* o = out + (size_t)row * HID_;
  ushort4 r0, r1;
  r0.x = f2bf((v0.x - mean) * rstd * w0.x + b0.x);
  r0.y = f2bf((v0.y - mean) * rstd * w0.y + b0.y);
  r0.z = f2bf((v0.z - mean) * rstd * w0.z + b0.z);
  r0.w = f2bf((v0.w - mean) * rstd * w0.w + b0.w);
  r1.x = f2bf((v1.x - mean) * rstd * w1.x + b1.x);
  r1.y = f2bf((v1.y - mean) * rstd * w1.y + b1.y);
  r1.z = f2bf((v1.z - mean) * rstd * w1.z + b1.z);
  r1.w = f2bf((v1.w - mean) * rstd * w1.w + b1.w);
  *(ushort4*)(o + lane * 4) = r0;
  *(ushort4*)(o + 256 + lane * 4) = r1;
}

// ---------------- MFMA GEMM 128x128, BK=64, global_load_lds + XOR swizzle ----------------
#define BM 128
#define BN 128
#define BK 64

template <int EPI, int OUTBF>
__global__ __launch_bounds__(256) void gemm_kernel(
    const unsigned short* __restrict__ A, const unsigned short* __restrict__ BT,
    void* __restrict__ Cv, int M, int N, int K,
    const float* __restrict__ bias, const float* __restrict__ resid) {
  __shared__ __align__(16) unsigned short As[BM * BK];
  __shared__ __align__(16) unsigned short Bs[BN * BK];
  int tid = threadIdx.x;
  int lane = tid & 63, wv = tid >> 6;
  int wm = wv >> 1, wn = wv & 1;
  int nwg = gridDim.x * gridDim.y;
  int flat = blockIdx.y * gridDim.x + blockIdx.x;
  int swz = (flat & 7) * (nwg >> 3) + (flat >> 3);
  int bx = swz % gridDim.x, by = swz / gridDim.x;
  int m0 = by * BM, n0 = bx * BN;
  f32x4 acc[4][4] = {};
  int rowblk = lane >> 3;
  int sblk = (lane & 7) ^ rowblk;
  int rA = wm * 64 + (lane & 15);
  int rB = wn * 64 + (lane & 15);
  for (int k0 = 0; k0 < K; k0 += BK) {
    __syncthreads();
    #pragma unroll
    for (int it = 0; it < 4; ++it) {
      int r0 = wv * 32 + it * 8;
      gload16(A + (size_t)(m0 + r0 + rowblk) * K + k0 + sblk * 8, &As[r0 * BK]);
      gload16(BT + (size_t)(n0 + r0 + rowblk) * K + k0 + sblk * 8, &Bs[r0 * BK]);
    }
    __syncthreads();
    #pragma unroll
    for (int kx = 0; kx < 2; ++kx) {
      int bidx = (lane >> 4) + kx * 4;
      bf16x8 fa[4], fb[4];
      #pragma unroll
      for (int i = 0; i < 4; ++i) {
        int ra = rA + i * 16;
        int rb = rB + i * 16;
        fa[i] = *(const bf16x8*)&As[ra * BK + ((bidx ^ (ra & 7)) << 3)];
        fb[i] = *(const bf16x8*)&Bs[rb * BK + ((bidx ^ (rb & 7)) << 3)];
      }
      #pragma unroll
      for (int i = 0; i < 4; ++i)
        #pragma unroll
        for (int j = 0; j < 4; ++j)
          acc[i][j] = __builtin_amdgcn_mfma_f32_16x16x32_bf16(fa[i], fb[j], acc[i][j], 0, 0, 0);
    }
  }
  int crow0 = m0 + wm * 64 + (lane >> 4) * 4, ccol0 = n0 + wn * 64 + (lane & 15);
  #pragma unroll
  for (int i = 0; i < 4; ++i) {
    #pragma unroll
    for (int j = 0; j < 4; ++j) {
      int col = ccol0 + j * 16;
      #pragma unroll
      for (int r = 0; r < 4; ++r) {
        int row = crow0 + i * 16 + r;
        float v = acc[i][j][r];
        if (EPI == 1) v += resid[(size_t)row * N + col];
        if (EPI == 2) { v += bias[col]; v = 0.5f * v * (1.f + erff(v * 0.70710678f)); }
        if (EPI == 3) v += bias[col] + resid[(size_t)row * N + col];
        if (OUTBF) ((unsigned short*)Cv)[(size_t)row * N + col] = f2bf(v);
        else       ((float*)Cv)[(size_t)row * N + col] = v;
      }
    }
  }
}

// ---------------- MFMA GEMM 64x128, BK=64, global_load_lds + XOR swizzle ----------------
template <int EPI, int OUTBF>
__global__ __launch_bounds__(256) void gemm64_kernel(
    const unsigned short* __restrict__ A, const unsigned short* __restrict__ BT,
    void* __restrict__ Cv, int M, int N, int K,
    const float* __restrict__ bias, const float* __restrict__ resid) {
  __shared__ __align__(16) unsigned short As[64 * BK];
  __shared__ __align__(16) unsigned short Bs[128 * BK];
  int tid = threadIdx.x;
  int lane = tid & 63, wv = tid >> 6;
  int wm = wv >> 1, wn = wv & 1;
  int nwg = gridDim.x * gridDim.y;
  int flat = blockIdx.y * gridDim.x + blockIdx.x;
  int swz = (flat & 7) * (nwg >> 3) + (flat >> 3);
  int bx = swz % gridDim.x, by = swz / gridDim.x;
  int m0 = by * 64, n0 = bx * BN;
  f32x4 acc[2][4] = {};
  int rowblk = lane >> 3;
  int sblk = (lane & 7) ^ rowblk;
  int rA = wm * 32 + (lane & 15);
  int rB = wn * 64 + (lane & 15);
  for (int k0 = 0; k0 < K; k0 += BK) {
    __syncthreads();
    #pragma unroll
    for (int it = 0; it < 2; ++it) {
      int r0 = wv * 16 + it * 8;
      gload16(A + (size_t)(m0 + r0 + rowblk) * K + k0 + sblk * 8, &As[r0 * BK]);
    }
    #pragma unroll
    for (int it = 0; it < 4; ++it) {
      int r0 = wv * 32 + it * 8;
      gload16(BT + (size_t)(n0 + r0 + rowblk) * K + k0 + sblk * 8, &Bs[r0 * BK]);
    }
    __syncthreads();
    #pragma unroll
    for (int kx = 0; kx < 2; ++kx) {
      int bidx = (lane >> 4) + kx * 4;
      bf16x8 fa[2], fb[4];
      #pragma unroll
      for (int i = 0; i < 2; ++i) {
        int ra = rA + i * 16;
        fa[i] = *(const bf16x8*)&As[ra * BK + ((bidx ^ (ra & 7)) << 3)];
      }
      #pragma unroll
      for (int j = 0; j < 4; ++j) {
        int rb = rB + j * 16;
        fb[j] = *(const bf16x8*)&Bs[rb * BK + ((bidx ^ (rb & 7)) << 3)];
      }
      #pragma unroll
      for (int i = 0; i < 2; ++i)
        #pragma unroll
        for (int j = 0; j < 4; ++j)
          acc[i][j] = __builtin_amdgcn_mfma_f32_16x16x32_bf16(fa[i], fb[j], acc[i][j], 0, 0, 0);
    }
  }
  int crow0 = m0 + wm * 32 + (lane >> 4) * 4, ccol0 = n0 + wn * 64 + (lane & 15);
  #pragma unroll
  for (int i = 0; i < 2; ++i) {
    #pragma unroll
    for (int j = 0; j < 4; ++j) {
      int col = ccol0 + j * 16;
      #pragma unroll
      for (int r = 0; r < 4; ++r) {
        int row = crow0 + i * 16 + r;
        float v = acc[i][j][r];
        if (EPI == 1) v += resid[(size_t)row * N + col];
        if (EPI == 2) { v += bias[col]; v = 0.5f * v * (1.f + erff(v * 0.70710678f)); }
        if (EPI == 3) v += bias[col] + resid[(size_t)row * N + col];
        if (OUTBF) ((unsigned short*)Cv)[(size_t)row * N + col] = f2bf(v);
        else       ((float*)Cv)[(size_t)row * N + col] = v;
      }
    }
  }
}

// ---------------- delta GEMM: softplus(spRank @ dtw^T + dtb) -> bf16 ----------------
__global__ __launch_bounds__(256) void dtgemm_kernel(
    const unsigned short* __restrict__ sp, const unsigned short* __restrict__ dtwB,
    const float* __restrict__ dtb, unsigned short* __restrict__ delta) {
  int kq = blockIdx.z;
  int m0 = blockIdx.y * 64, n0 = blockIdx.x * 128;
  __shared__ __align__(16) unsigned short As[64 * 32];
  __shared__ __align__(16) unsigned short Bs[128 * 32];
  int tid = threadIdx.x, lane = tid & 63, wv = tid >> 6;
  int wm = wv >> 1, wn = wv & 1;
  {
    int r = tid >> 2, c = (tid & 3) * 8;
    *(uint4*)&As[r * 32 + c] = *(const uint4*)(sp + (size_t)(m0 + r) * 384 + kq * 32 + c);
  }
  {
    int r = tid >> 1, c = (tid & 1) * 16;
    const unsigned short* p = dtwB + (size_t)(kq * DI_ + n0 + r) * 32 + c;
    *(uint4*)&Bs[r * 32 + c] = *(const uint4*)(p);
    *(uint4*)&Bs[r * 32 + c + 8] = *(const uint4*)(p + 8);
  }
  __syncthreads();
  int kk = (lane >> 4) * 8;
  int rA = wm * 32 + (lane & 15);
  int rB = wn * 64 + (lane & 15);
  f32x4 acc[2][4] = {};
  bf16x8 fa[2], fb[4];
  #pragma unroll
  for (int i = 0; i < 2; ++i) fa[i] = *(const bf16x8*)&As[(rA + i * 16) * 32 + kk];
  #pragma unroll
  for (int j = 0; j < 4; ++j) fb[j] = *(const bf16x8*)&Bs[(rB + j * 16) * 32 + kk];
  #pragma unroll
  for (int i = 0; i < 2; ++i)
    #pragma unroll
    for (int j = 0; j < 4; ++j)
      acc[i][j] = __builtin_amdgcn_mfma_f32_16x16x32_bf16(fa[i], fb[j], acc[i][j], 0, 0, 0);
  int crow0 = m0 + wm * 32 + (lane >> 4) * 4, ccol0 = n0 + wn * 64 + (lane & 15);
  #pragma unroll
  for (int i = 0; i < 2; ++i) {
    #pragma unroll
    for (int j = 0; j < 4; ++j) {
      int col = ccol0 + j * 16;
      float bias = dtb[kq * DI_ + col];
      #pragma unroll
      for (int r = 0; r < 4; ++r) {
        int row = crow0 + i * 16 + r;
        float v = acc[i][j][r] + bias;
        v = (v > 15.f) ? v : log1pf(__expf(v));
        int bb = row >> 10, l = row & 1023;
        delta[(((size_t)(bb * 4 + kq)) << 20) + ((size_t)l << 10) + col] = f2bf(v);
      }
    }
  }
}

// ---------------- depthwise 3x3 conv + bias + SiLU; bf16 in (xz), bf16 out ----------------
__global__ __launch_bounds__(256) void conv_kernel(
    const unsigned short* __restrict__ xz, const float* __restrict__ cw,
    const float* __restrict__ cb, unsigned short* __restrict__ xa) {
  int idx = blockIdx.x * 256 + threadIdx.x;
  int d = idx & (DI_ - 1);
  int l = (idx >> 10) & (L_ - 1);
  int b = idx >> 20;
  int hh = l >> 5, ww = l & 31;
  float acc = cb[d];
  #pragma unroll
  for (int dh = -1; dh <= 1; ++dh) {
    int y = hh + dh;
    if ((unsigned)y >= 32u) continue;
    #pragma unroll
    for (int dw = -1; dw <= 1; ++dw) {
      int x = ww + dw;
      if ((unsigned)x >= 32u) continue;
      acc = fmaf(bf2f(xz[((size_t)b * L_ + y * 32 + x) * (2 * DI_) + d]),
                 cw[d * 9 + (dh + 1) * 3 + (dw + 1)], acc);
    }
  }
  float sv = acc / (1.f + __expf(-acc));
  xa[idx] = f2bf(sv);
}

// ---------------- selective scan: interleaved bf16 BC (one b128/step) ----------------
// lane = dg*16 + ng: dg = lane>>4 (4 d per wave), ng = lane&15 (4 n per lane).
// Block 512 thr = 8 waves = 32 d. Grid (DI/32, K, B) = 512 blocks -> 4 wv/SIMD.
// Per step DS: BC b128 (bf16 {B[4],C[4]}) + DLU b128 per 2 steps + yq b32 write ~ 24 cyc.
#define CH 16
#define NCH (L_ / CH)
#define DLP 36
#define YQP 6
__global__ __launch_bounds__(512) void scan_kernel(
    unsigned short* __restrict__ ybuf, const unsigned short* __restrict__ xa,
    const unsigned short* __restrict__ sp, const unsigned short* __restrict__ Cs,
    const unsigned short* __restrict__ dltb,
    const float* __restrict__ A_logs, const float* __restrict__ Ds) {
  int dblk = blockIdx.x;
  int k = blockIdx.y, b = blockIdx.z;
  int tid = threadIdx.x, lane = tid & 63, wv = tid >> 6;
  int dg = lane >> 4, ng = lane & 15;
  int qp = (lane >> 2) & 3;
  int wd = wv * 4 + dg;
  int gd = k * DI_ + dblk * 32 + wd;
  v2f a2p[2], h2[2];
  #pragma unroll
  for (int j = 0; j < 2; ++j) {
    a2p[j].x = -__expf(A_logs[(size_t)gd * N_ + ng * 4 + 2 * j]) * 1.44269504f;
    a2p[j].y = -__expf(A_logs[(size_t)gd * N_ + ng * 4 + 2 * j + 1]) * 1.44269504f;
    h2[j].x = 0.f; h2[j].y = 0.f;
  }

  __shared__ __align__(16) unsigned short BCsh[2][CH][16][8];  // bf16 {B[4n..], C[4n..]}
  __shared__ float DLU[2][32][DLP];
  __shared__ float yq[CH][32][YQP];
  __shared__ float dsh[32];

  const size_t spB = (size_t)b * L_ * 384 + 128 + k * 64;  // bf16 elems
  const size_t csB = (size_t)b * L_ * 256 + k * 64;        // bf16 elems
  const size_t dlB = ((size_t)(b * 4 + k) * L_) * DI_ + dblk * 32;
  const size_t xaB = (size_t)b * L_ * DI_ + dblk * 32;

  if (tid < 32) dsh[tid] = Ds[k * DI_ + dblk * 32 + tid];

  int liS = tid >> 5, js = tid & 31;
  int gS = js >> 1, oS = (js & 1) * 2;  // BC staging slot
  int liE = tid >> 5, dd = tid & 31;    // epilogue role
  auto posf = [&](int l) {
    int lr = 1023 - l;
    return (k == 0) ? l
         : (k == 1) ? ((l & 31) * 32 + (l >> 5))
         : (k == 2) ? lr
                    : ((lr & 31) * 32 + (lr >> 5));
  };

  // stage chunk 0
  {
    unsigned int pB = *(const unsigned int*)(sp + spB + (size_t)liS * 384 + js * 2);
    unsigned int pC = *(const unsigned int*)(Cs + csB + (size_t)liS * 256 + js * 2);
    *(unsigned int*)&BCsh[0][liS][gS][oS] = pB;
    *(unsigned int*)&BCsh[0][liS][gS][4 + oS] = pC;
    float2 p;
    p.x = bf2f(dltb[dlB + (size_t)liS * DI_ + js]);
    p.y = bf2f(xa[xaB + (size_t)posf(liS) * DI_ + js]);
    *(float2*)&DLU[0][js][liS * 2] = p;
  }
  __syncthreads();

  int cur = 0;
  for (int c = 0; c < NCH; ++c) {
    unsigned int pB, pC;
    unsigned short pD, pU;
    if (c < NCH - 1) {
      int lb = (c + 1) * CH + liS;
      pB = *(const unsigned int*)(sp + spB + (size_t)lb * 384 + js * 2);
      pC = *(const unsigned int*)(Cs + csB + (size_t)lb * 256 + js * 2);
      pD = dltb[dlB + (size_t)lb * DI_ + js];
      pU = xa[xaB + (size_t)posf(lb) * DI_ + js];
    }
    #pragma unroll
    for (int li2 = 0; li2 < CH; li2 += 2) {
      f32x4 duq = *(const f32x4*)&DLU[cur][wd][li2 * 2];
      #pragma unroll
      for (int s = 0; s < 2; ++s) {
        int li = li2 + s;
        float dlt = s ? duq[2] : duq[0];
        float u   = s ? duq[3] : duq[1];
        float du = dlt * u;
        uint4 bc = *(const uint4*)&BCsh[cur][li][ng][0];
        v2f b01 = bfp2v(bc.x);
        v2f b23 = bfp2v(bc.y);
        v2f c01 = bfp2v(bc.z);
        v2f c23 = bfp2v(bc.w);
        v2f dlt2; dlt2.x = dlt; dlt2.y = dlt;
        v2f du2;  du2.x = du;  du2.y = du;
        v2f arg0 = dlt2 * a2p[0];
        v2f arg1 = dlt2 * a2p[1];
        v2f e0, e1;
        e0.x = __builtin_amdgcn_exp2f(arg0.x);
        e0.y = __builtin_amdgcn_exp2f(arg0.y);
        e1.x = __builtin_amdgcn_exp2f(arg1.x);
        e1.y = __builtin_amdgcn_exp2f(arg1.y);
        h2[0] = e0 * h2[0] + du2 * b01;
        h2[1] = e1 * h2[1] + du2 * b23;
        v2f yv = h2[0] * c01 + h2[1] * c23;
        float yp = yv.x + yv.y;
        yp = dpp_add<0xB1>(yp);   // quad xor1
        yp = dpp_add<0x4E>(yp);   // quad xor2 -> 16-n quad partial
        yq[li][wd][qp] = yp;      // 4 quad lanes same value/addr (benign)
      }
    }
    __syncthreads();  // yq complete; DLU[cur] still valid
    {  // epilogue: one y output per thread
      float2 q01 = *(const float2*)&yq[liE][dd][0];
      float2 q23 = *(const float2*)&yq[liE][dd][2];
      float y = (q01.x + q01.y) + (q23.x + q23.y);
      float u = DLU[cur][dd][liE * 2 + 1];
      y = fmaf(u, dsh[dd], y);
      ybuf[dlB + (size_t)(c * CH + liE) * DI_ + dd] = f2bf(y);
    }
    if (c < NCH - 1) {
      int nxt = cur ^ 1;
      *(unsigned int*)&BCsh[nxt][liS][gS][oS] = pB;
      *(unsigned int*)&BCsh[nxt][liS][gS][4 + oS] = pC;
      float2 p; p.x = bf2f(pD); p.y = bf2f(pU);
      *(float2*)&DLU[nxt][js][liS * 2] = p;
    }
    __syncthreads();  // staging visible; yq free for next chunk
    cur ^= 1;
  }
}

// ---------------- fuse: ygz = (sum_k yk) * z  (yk bf16, z bf16) -> bf16 ----------------
__global__ __launch_bounds__(256) void fuse_ygz(
    const unsigned short* __restrict__ yk, const unsigned short* __restrict__ xz,
    unsigned short* __restrict__ ygz) {
  size_t i = ((size_t)blockIdx.x * 256 + threadIdx.x) * 8;
  size_t b = i >> 20, ld = i & ((1u << 20) - 1);
  float acc[8] = {};
  #pragma unroll
  for (int k = 0; k < 4; ++k) {
    uint4 v = *(const uint4*)(yk + ((size_t)(b * 4 + k) << 20) + ld);
    unsigned int w[4] = {v.x, v.y, v.z, v.w};
    #pragma unroll
    for (int t = 0; t < 4; ++t) {
      acc[t * 2 + 0] += __builtin_bit_cast(float, w[t] << 16);
      acc[t * 2 + 1] += __builtin_bit_cast(float, w[t] & 0xFFFF0000u);
    }
  }
  uint4 zv = *(const uint4*)(xz + (i >> 10) * (2 * DI_) + DI_ + (i & (DI_ - 1)));
  unsigned int zw[4] = {zv.x, zv.y, zv.z, zv.w};
  float z[8];
  #pragma unroll
  for (int t = 0; t < 4; ++t) {
    z[t * 2 + 0] = __builtin_bit_cast(float, zw[t] << 16);
    z[t * 2 + 1] = __builtin_bit_cast(float, zw[t] & 0xFFFF0000u);
  }
  uint4 o;
  o.x = (unsigned int)f2bf(acc[0] * z[0]) | ((unsigned int)f2bf(acc[1] * z[1]) << 16);
  o.y = (unsigned int)f2bf(acc[2] * z[2]) | ((unsigned int)f2bf(acc[3] * z[3]) << 16);
  o.z = (unsigned int)f2bf(acc[4] * z[4]) | ((unsigned int)f2bf(acc[5] * z[5]) << 16);
  o.w = (unsigned int)f2bf(acc[6] * z[6]) | ((unsigned int)f2bf(acc[7] * z[7]) << 16);
  *(uint4*)(ygz + i) = o;
}

// ---------------- host ----------------
extern "C" void kernel_launch(void* const* d_in, const int* in_sizes, int n_in,
                              void* d_out, int out_size, void* d_ws, size_t ws_size,
                              hipStream_t stream) {
  (void)in_sizes; (void)n_in; (void)out_size; (void)ws_size;
  const float* content   = (const float*)d_in[0];
  const float* style     = (const float*)d_in[1];
  const float* norm1_w   = (const float*)d_in[2];
  const float* norm1_b   = (const float*)d_in[3];
  const float* in_proj_w = (const float*)d_in[4];
  const float* conv_w    = (const float*)d_in[5];
  const float* conv_b    = (const float*)d_in[6];
  const float* style_proj_w   = (const float*)d_in[7];
  const float* content_proj_w = (const float*)d_in[8];
  const float* dtw       = (const float*)d_in[9];
  const float* dtb       = (const float*)d_in[10];
  const float* A_logs    = (const float*)d_in[11];
  const float* Ds        = (const float*)d_in[12];
  const float* out_proj_w = (const float*)d_in[13];
  const float* norm2_w   = (const float*)d_in[14];
  const float* norm2_b   = (const float*)d_in[15];
  const float* mlp_w1    = (const float*)d_in[16];
  const float* mlp_b1    = (const float*)d_in[17];
  const float* mlp_w2    = (const float*)d_in[18];
  const float* mlp_b2    = (const float*)d_in[19];
  float* out = (float*)d_out;

  float* ws = (float*)d_ws;
  const size_t ROWS = (size_t)B_ * L_;
  const size_t SCAN_ELEMS = (size_t)B_ * K_ * L_ * DI_;
  size_t o = 0;
  unsigned short* cn  = (unsigned short*)(ws + o); o += ROWS * HID_ / 2;
  unsigned short* sn  = (unsigned short*)(ws + o); o += ROWS * HID_ / 2;
  unsigned short* xn  = (unsigned short*)(ws + o); o += ROWS * HID_ / 2;
  unsigned short* xz  = (unsigned short*)(ws + o); o += ROWS * 2 * DI_ / 2;
  unsigned short* sp  = (unsigned short*)(ws + o); o += ROWS * 384 / 2;
  unsigned short* xa  = (unsigned short*)(ws + o); o += ROWS * DI_ / 2;
  unsigned short* csb = (unsigned short*)(ws + o); o += ROWS * 256 / 2;
  float* x1    = ws + o; o += ROWS * HID_;
  unsigned short* dltb = (unsigned short*)(ws + o); o += SCAN_ELEMS / 2;
  unsigned short* ybuf = (unsigned short*)(ws + o); o += SCAN_ELEMS / 2;
  unsigned short* ygz  = (unsigned short*)(ws + o); o += ROWS * DI_ / 2;
  unsigned short* wt = (unsigned short*)(ws + o);
  unsigned short* inpT = wt;
  unsigned short* styT = inpT + 2048 * 512;
  unsigned short* conT = styT + 384 * 512;
  unsigned short* outT = conT + 256 * 1024;
  unsigned short* w1T  = outT + 512 * 1024;
  unsigned short* w2T  = w1T + 2048 * 512;
  unsigned short* dtwB = w2T + 512 * 2048;
  unsigned short* hmid = ybuf;

  transpose_all<<<4032, 256, 0, stream>>>(
      in_proj_w, style_proj_w, content_proj_w, out_proj_w, mlp_w1, mlp_w2,
      inpT, styT, conT, outT, w1T, w2T);
  cast_bf<<<(K_ * DI_ * R_) / 1024, 256, 0, stream>>>(dtw, dtwB);

  ln_kernel<<<dim3(ROWS / 4, 2), 256, 0, stream>>>(content, cn, style, sn, norm1_w, norm1_b);

  gemm_kernel<0, 1><<<dim3(2048 / BN, ROWS / BM), 256, 0, stream>>>(
      cn, inpT, xz, ROWS, 2048, 512, nullptr, nullptr);
  gemm64_kernel<0, 1><<<dim3(384 / BN, ROWS / 64), 256, 0, stream>>>(
      sn, styT, sp, ROWS, 384, 512, nullptr, nullptr);
  conv_kernel<<<(ROWS * DI_) / 256, 256, 0, stream>>>(xz, conv_w, conv_b, xa);
  gemm64_kernel<0, 1><<<dim3(256 / BN, ROWS / 64), 256, 0, stream>>>(
      xa, conT, csb, ROWS, 256, 1024, nullptr, nullptr);
  dtgemm_kernel<<<dim3(DI_ / 128, ROWS / 64, K_), 256, 0, stream>>>(sp, dtwB, dtb, dltb);
  scan_kernel<<<dim3(DI_ / 32, K_, B_), 512, 0, stream>>>(
      ybuf, xa, sp, csb, dltb, A_logs, Ds);
  fuse_ygz<<<(ROWS * DI_) / (256 * 8), 256, 0, stream>>>(ybuf, xz, ygz);
  gemm64_kernel<1, 0><<<dim3(512 / BN, ROWS / 64), 256, 0, stream>>>(
      ygz, outT, x1, ROWS, 512, 1024, nullptr, content);
  ln_kernel<<<dim3(ROWS / 4, 1), 256, 0, stream>>>(x1, xn, nullptr, nullptr, norm2_w, norm2_b);
  gemm_kernel<2, 1><<<dim3(2048 / BN, ROWS / BM), 256, 0, stream>>>(
      xn, w1T, hmid, ROWS, 2048, 512, mlp_b1, nullptr);
  gemm64_kernel<3, 0><<<dim3(512 / BN, ROWS / 64), 256, 0, stream>>>(
      hmid, w2T, out, ROWS, 512, 2048, mlp_b2, x1);
}

// Round 14
// 445.194 us; speedup vs baseline: 1.0893x; 1.0893x over previous
//
#include <hip/hip_runtime.h>

// ---------------- constants ----------------
#define B_ 4
#define Hh_ 32
#define Ww_ 32
#define L_ 1024
#define HID_ 512
#define DI_ 1024
#define N_ 64
#define R_ 32
#define K_ 4
#define MLP_ 2048

typedef __bf16 bf16x8 __attribute__((ext_vector_type(8)));
typedef float f32x4 __attribute__((ext_vector_type(4)));
typedef float v2f __attribute__((ext_vector_type(2)));

__device__ __forceinline__ unsigned short f2bf(float f) {
  unsigned int u = __builtin_bit_cast(unsigned int, f);
  return (unsigned short)((u + 0x7FFFu + ((u >> 16) & 1u)) >> 16);
}
__device__ __forceinline__ float bf2f(unsigned short h) {
  return __builtin_bit_cast(float, (unsigned int)h << 16);
}
__device__ __forceinline__ float2 bfp2f(unsigned int u) {
  float2 r;
  r.x = __builtin_bit_cast(float, u << 16);
  r.y = __builtin_bit_cast(float, u & 0xFFFF0000u);
  return r;
}

// async global->LDS, 16B per lane; lds base must be wave-uniform
__device__ __forceinline__ void gload16(const unsigned short* g, unsigned short* l) {
  __builtin_amdgcn_global_load_lds(
      (const __attribute__((address_space(1))) unsigned int*)g,
      (__attribute__((address_space(3))) unsigned int*)l, 16, 0, 0);
}

// DPP add: x + x[perm(lane)] on the VALU pipe (no DS traffic)
template <int CTRL>
__device__ __forceinline__ float dpp_add(float x) {
  int i = __builtin_bit_cast(int, x);
  int j = __builtin_amdgcn_update_dpp(i, i, CTRL, 0xF, 0xF, false);
  return x + __builtin_bit_cast(float, j);
}

// ---------------- all 6 weight transposes in ONE launch ----------------
__global__ __launch_bounds__(256) void transpose_all(
    const float* __restrict__ s0, const float* __restrict__ s1,
    const float* __restrict__ s2, const float* __restrict__ s3,
    const float* __restrict__ s4, const float* __restrict__ s5,
    unsigned short* __restrict__ t0, unsigned short* __restrict__ t1,
    unsigned short* __restrict__ t2, unsigned short* __restrict__ t3,
    unsigned short* __restrict__ t4, unsigned short* __restrict__ t5) {
  __shared__ float t[32][33];
  int bid = blockIdx.x;
  const float* src; unsigned short* dst; int K, N, bx, by;
  if (bid < 1024)      { src = s0; dst = t0; K = 512;  N = 2048; int r = bid;        bx = r & 63; by = r >> 6; }
  else if (bid < 1216) { src = s1; dst = t1; K = 512;  N = 384;  int r = bid - 1024; bx = r % 12; by = r / 12; }
  else if (bid < 1472) { src = s2; dst = t2; K = 1024; N = 256;  int r = bid - 1216; bx = r & 7;  by = r >> 3; }
  else if (bid < 1984) { src = s3; dst = t3; K = 1024; N = 512;  int r = bid - 1472; bx = r & 15; by = r >> 4; }
  else if (bid < 3008) { src = s4; dst = t4; K = 512;  N = 2048; int r = bid - 1984; bx = r & 63; by = r >> 6; }
  else                 { src = s5; dst = t5; K = 2048; N = 512;  int r = bid - 3008; bx = r & 15; by = r >> 4; }
  int nb = bx * 32, kb = by * 32;
  int tx = threadIdx.x & 31, ty = threadIdx.x >> 5;
  for (int r = ty; r < 32; r += 8) t[r][tx] = src[(size_t)(kb + r) * N + nb + tx];
  __syncthreads();
  for (int r = ty; r < 32; r += 8) dst[(size_t)(nb + r) * K + kb + tx] = f2bf(t[tx][r]);
}

// ---------------- cast f32 -> bf16 (for dtw) ----------------
__global__ __launch_bounds__(256) void cast_bf(
    const float* __restrict__ src, unsigned short* __restrict__ dst) {
  int i = (blockIdx.x * 256 + threadIdx.x) * 4;
  float4 v = *(const float4*)(src + i);
  ushort4 o = {f2bf(v.x), f2bf(v.y), f2bf(v.z), f2bf(v.w)};
  *(ushort4*)(dst + i) = o;
}

// ---------------- LayerNorm over 512, wave per row; writes bf16 ----------------
__global__ __launch_bounds__(256) void ln_kernel(
    const float* __restrict__ in0, unsigned short* __restrict__ out0,
    const float* __restrict__ in1, unsigned short* __restrict__ out1,
    const float* __restrict__ w, const float* __restrict__ bb) {
  const float* in = blockIdx.y ? in1 : in0;
  unsigned short* out = blockIdx.y ? out1 : out0;
  int row = blockIdx.x * 4 + (threadIdx.x >> 6);
  int lane = threadIdx.x & 63;
  const float* p = in + (size_t)row * HID_;
  float4 v0 = *(const float4*)(p + lane * 4);
  float4 v1 = *(const float4*)(p + 256 + lane * 4);
  float s = v0.x + v0.y + v0.z + v0.w + v1.x + v1.y + v1.z + v1.w;
  float q = v0.x * v0.x + v0.y * v0.y + v0.z * v0.z + v0.w * v0.w +
            v1.x * v1.x + v1.y * v1.y + v1.z * v1.z + v1.w * v1.w;
  #pragma unroll
  for (int m = 1; m < 64; m <<= 1) { s += __shfl_xor(s, m, 64); q += __shfl_xor(q, m, 64); }
  float mean = s * (1.f / 512.f);
  float var = q * (1.f / 512.f) - mean * mean;
  float rstd = rsqrtf(var + 1e-5f);
  float4 w0 = *(const float4*)(w + lane * 4);
  float4 w1 = *(const float4*)(w + 256 + lane * 4);
  float4 b0 = *(const float4*)(bb + lane * 4);
  float4 b1 = *(const float4*)(bb + 256 + lane * 4);
  unsigned short* o = out + (size_t)row * HID_;
  ushort4 r0, r1;
  r0.x = f2bf((v0.x - mean) * rstd * w0.x + b0.x);
  r0.y = f2bf((v0.y - mean) * rstd * w0.y + b0.y);
  r0.z = f2bf((v0.z - mean) * rstd * w0.z + b0.z);
  r0.w = f2bf((v0.w - mean) * rstd * w0.w + b0.w);
  r1.x = f2bf((v1.x - mean) * rstd * w1.x + b1.x);
  r1.y = f2bf((v1.y - mean) * rstd * w1.y + b1.y);
  r1.z = f2bf((v1.z - mean) * rstd * w1.z + b1.z);
  r1.w = f2bf((v1.w - mean) * rstd * w1.w + b1.w);
  *(ushort4*)(o + lane * 4) = r0;
  *(ushort4*)(o + 256 + lane * 4) = r1;
}

// ---------------- MFMA GEMM 128x128, BK=64, global_load_lds + XOR swizzle ----------------
#define BM 128
#define BN 128
#define BK 64

template <int EPI, int OUTBF>
__global__ __launch_bounds__(256) void gemm_kernel(
    const unsigned short* __restrict__ A, const unsigned short* __restrict__ BT,
    void* __restrict__ Cv, int M, int N, int K,
    const float* __restrict__ bias, const float* __restrict__ resid) {
  __shared__ __align__(16) unsigned short As[BM * BK];
  __shared__ __align__(16) unsigned short Bs[BN * BK];
  int tid = threadIdx.x;
  int lane = tid & 63, wv = tid >> 6;
  int wm = wv >> 1, wn = wv & 1;
  int nwg = gridDim.x * gridDim.y;
  int flat = blockIdx.y * gridDim.x + blockIdx.x;
  int swz = (flat & 7) * (nwg >> 3) + (flat >> 3);
  int bx = swz % gridDim.x, by = swz / gridDim.x;
  int m0 = by * BM, n0 = bx * BN;
  f32x4 acc[4][4] = {};
  int rowblk = lane >> 3;
  int sblk = (lane & 7) ^ rowblk;
  int rA = wm * 64 + (lane & 15);
  int rB = wn * 64 + (lane & 15);
  for (int k0 = 0; k0 < K; k0 += BK) {
    __syncthreads();
    #pragma unroll
    for (int it = 0; it < 4; ++it) {
      int r0 = wv * 32 + it * 8;
      gload16(A + (size_t)(m0 + r0 + rowblk) * K + k0 + sblk * 8, &As[r0 * BK]);
      gload16(BT + (size_t)(n0 + r0 + rowblk) * K + k0 + sblk * 8, &Bs[r0 * BK]);
    }
    __syncthreads();
    #pragma unroll
    for (int kx = 0; kx < 2; ++kx) {
      int bidx = (lane >> 4) + kx * 4;
      bf16x8 fa[4], fb[4];
      #pragma unroll
      for (int i = 0; i < 4; ++i) {
        int ra = rA + i * 16;
        int rb = rB + i * 16;
        fa[i] = *(const bf16x8*)&As[ra * BK + ((bidx ^ (ra & 7)) << 3)];
        fb[i] = *(const bf16x8*)&Bs[rb * BK + ((bidx ^ (rb & 7)) << 3)];
      }
      #pragma unroll
      for (int i = 0; i < 4; ++i)
        #pragma unroll
        for (int j = 0; j < 4; ++j)
          acc[i][j] = __builtin_amdgcn_mfma_f32_16x16x32_bf16(fa[i], fb[j], acc[i][j], 0, 0, 0);
    }
  }
  int crow0 = m0 + wm * 64 + (lane >> 4) * 4, ccol0 = n0 + wn * 64 + (lane & 15);
  #pragma unroll
  for (int i = 0; i < 4; ++i) {
    #pragma unroll
    for (int j = 0; j < 4; ++j) {
      int col = ccol0 + j * 16;
      #pragma unroll
      for (int r = 0; r < 4; ++r) {
        int row = crow0 + i * 16 + r;
        float v = acc[i][j][r];
        if (EPI == 1) v += resid[(size_t)row * N + col];
        if (EPI == 2) { v += bias[col]; v = 0.5f * v * (1.f + erff(v * 0.70710678f)); }
        if (EPI == 3) v += bias[col] + resid[(size_t)row * N + col];
        if (OUTBF) ((unsigned short*)Cv)[(size_t)row * N + col] = f2bf(v);
        else       ((float*)Cv)[(size_t)row * N + col] = v;
      }
    }
  }
}

// ---------------- MFMA GEMM 64x128, BK=64, global_load_lds + XOR swizzle ----------------
template <int EPI, int OUTBF>
__global__ __launch_bounds__(256) void gemm64_kernel(
    const unsigned short* __restrict__ A, const unsigned short* __restrict__ BT,
    void* __restrict__ Cv, int M, int N, int K,
    const float* __restrict__ bias, const float* __restrict__ resid) {
  __shared__ __align__(16) unsigned short As[64 * BK];
  __shared__ __align__(16) unsigned short Bs[128 * BK];
  int tid = threadIdx.x;
  int lane = tid & 63, wv = tid >> 6;
  int wm = wv >> 1, wn = wv & 1;
  int nwg = gridDim.x * gridDim.y;
  int flat = blockIdx.y * gridDim.x + blockIdx.x;
  int swz = (flat & 7) * (nwg >> 3) + (flat >> 3);
  int bx = swz % gridDim.x, by = swz / gridDim.x;
  int m0 = by * 64, n0 = bx * BN;
  f32x4 acc[2][4] = {};
  int rowblk = lane >> 3;
  int sblk = (lane & 7) ^ rowblk;
  int rA = wm * 32 + (lane & 15);
  int rB = wn * 64 + (lane & 15);
  for (int k0 = 0; k0 < K; k0 += BK) {
    __syncthreads();
    #pragma unroll
    for (int it = 0; it < 2; ++it) {
      int r0 = wv * 16 + it * 8;
      gload16(A + (size_t)(m0 + r0 + rowblk) * K + k0 + sblk * 8, &As[r0 * BK]);
    }
    #pragma unroll
    for (int it = 0; it < 4; ++it) {
      int r0 = wv * 32 + it * 8;
      gload16(BT + (size_t)(n0 + r0 + rowblk) * K + k0 + sblk * 8, &Bs[r0 * BK]);
    }
    __syncthreads();
    #pragma unroll
    for (int kx = 0; kx < 2; ++kx) {
      int bidx = (lane >> 4) + kx * 4;
      bf16x8 fa[2], fb[4];
      #pragma unroll
      for (int i = 0; i < 2; ++i) {
        int ra = rA + i * 16;
        fa[i] = *(const bf16x8*)&As[ra * BK + ((bidx ^ (ra & 7)) << 3)];
      }
      #pragma unroll
      for (int j = 0; j < 4; ++j) {
        int rb = rB + j * 16;
        fb[j] = *(const bf16x8*)&Bs[rb * BK + ((bidx ^ (rb & 7)) << 3)];
      }
      #pragma unroll
      for (int i = 0; i < 2; ++i)
        #pragma unroll
        for (int j = 0; j < 4; ++j)
          acc[i][j] = __builtin_amdgcn_mfma_f32_16x16x32_bf16(fa[i], fb[j], acc[i][j], 0, 0, 0);
    }
  }
  int crow0 = m0 + wm * 32 + (lane >> 4) * 4, ccol0 = n0 + wn * 64 + (lane & 15);
  #pragma unroll
  for (int i = 0; i < 2; ++i) {
    #pragma unroll
    for (int j = 0; j < 4; ++j) {
      int col = ccol0 + j * 16;
      #pragma unroll
      for (int r = 0; r < 4; ++r) {
        int row = crow0 + i * 16 + r;
        float v = acc[i][j][r];
        if (EPI == 1) v += resid[(size_t)row * N + col];
        if (EPI == 2) { v += bias[col]; v = 0.5f * v * (1.f + erff(v * 0.70710678f)); }
        if (EPI == 3) v += bias[col] + resid[(size_t)row * N + col];
        if (OUTBF) ((unsigned short*)Cv)[(size_t)row * N + col] = f2bf(v);
        else       ((float*)Cv)[(size_t)row * N + col] = v;
      }
    }
  }
}

// ---------------- delta GEMM: softplus(spRank @ dtw^T + dtb) -> bf16 ----------------
__global__ __launch_bounds__(256) void dtgemm_kernel(
    const unsigned short* __restrict__ sp, const unsigned short* __restrict__ dtwB,
    const float* __restrict__ dtb, unsigned short* __restrict__ delta) {
  int kq = blockIdx.z;
  int m0 = blockIdx.y * 64, n0 = blockIdx.x * 128;
  __shared__ __align__(16) unsigned short As[64 * 32];
  __shared__ __align__(16) unsigned short Bs[128 * 32];
  int tid = threadIdx.x, lane = tid & 63, wv = tid >> 6;
  int wm = wv >> 1, wn = wv & 1;
  {
    int r = tid >> 2, c = (tid & 3) * 8;
    *(uint4*)&As[r * 32 + c] = *(const uint4*)(sp + (size_t)(m0 + r) * 384 + kq * 32 + c);
  }
  {
    int r = tid >> 1, c = (tid & 1) * 16;
    const unsigned short* p = dtwB + (size_t)(kq * DI_ + n0 + r) * 32 + c;
    *(uint4*)&Bs[r * 32 + c] = *(const uint4*)(p);
    *(uint4*)&Bs[r * 32 + c + 8] = *(const uint4*)(p + 8);
  }
  __syncthreads();
  int kk = (lane >> 4) * 8;
  int rA = wm * 32 + (lane & 15);
  int rB = wn * 64 + (lane & 15);
  f32x4 acc[2][4] = {};
  bf16x8 fa[2], fb[4];
  #pragma unroll
  for (int i = 0; i < 2; ++i) fa[i] = *(const bf16x8*)&As[(rA + i * 16) * 32 + kk];
  #pragma unroll
  for (int j = 0; j < 4; ++j) fb[j] = *(const bf16x8*)&Bs[(rB + j * 16) * 32 + kk];
  #pragma unroll
  for (int i = 0; i < 2; ++i)
    #pragma unroll
    for (int j = 0; j < 4; ++j)
      acc[i][j] = __builtin_amdgcn_mfma_f32_16x16x32_bf16(fa[i], fb[j], acc[i][j], 0, 0, 0);
  int crow0 = m0 + wm * 32 + (lane >> 4) * 4, ccol0 = n0 + wn * 64 + (lane & 15);
  #pragma unroll
  for (int i = 0; i < 2; ++i) {
    #pragma unroll
    for (int j = 0; j < 4; ++j) {
      int col = ccol0 + j * 16;
      float bias = dtb[kq * DI_ + col];
      #pragma unroll
      for (int r = 0; r < 4; ++r) {
        int row = crow0 + i * 16 + r;
        float v = acc[i][j][r] + bias;
        v = (v > 15.f) ? v : log1pf(__expf(v));
        int bb = row >> 10, l = row & 1023;
        delta[(((size_t)(bb * 4 + kq)) << 20) + ((size_t)l << 10) + col] = f2bf(v);
      }
    }
  }
}

// ---------------- depthwise 3x3 conv + bias + SiLU; bf16 in (xz), bf16 out ----------------
__global__ __launch_bounds__(256) void conv_kernel(
    const unsigned short* __restrict__ xz, const float* __restrict__ cw,
    const float* __restrict__ cb, unsigned short* __restrict__ xa) {
  int idx = blockIdx.x * 256 + threadIdx.x;
  int d = idx & (DI_ - 1);
  int l = (idx >> 10) & (L_ - 1);
  int b = idx >> 20;
  int hh = l >> 5, ww = l & 31;
  float acc = cb[d];
  #pragma unroll
  for (int dh = -1; dh <= 1; ++dh) {
    int y = hh + dh;
    if ((unsigned)y >= 32u) continue;
    #pragma unroll
    for (int dw = -1; dw <= 1; ++dw) {
      int x = ww + dw;
      if ((unsigned)x >= 32u) continue;
      acc = fmaf(bf2f(xz[((size_t)b * L_ + y * 32 + x) * (2 * DI_) + d]),
                 cw[d * 9 + (dh + 1) * 3 + (dw + 1)], acc);
    }
  }
  float sv = acc / (1.f + __expf(-acc));
  xa[idx] = f2bf(sv);
}

// ---------------- selective scan: r11 structure (f32 LDS B/C, quad-partial reduce) ----------------
// lane = dg*16 + ng: dg = lane>>4 (4 d per wave), ng = lane&15 (4 n per lane).
// Block 512 thr = 8 waves = 32 d. Grid (DI/32, K, B) = 512 blocks -> 4 wv/SIMD.
// bf16 global inputs converted to f32 at staging (amortized); inner loop all-f32, no unpack.
#define CH 16
#define NCH (L_ / CH)
#define DLP 36
#define YQP 6
__global__ __launch_bounds__(512) void scan_kernel(
    unsigned short* __restrict__ ybuf, const unsigned short* __restrict__ xa,
    const unsigned short* __restrict__ sp, const unsigned short* __restrict__ Cs,
    const unsigned short* __restrict__ dltb,
    const float* __restrict__ A_logs, const float* __restrict__ Ds) {
  int dblk = blockIdx.x;
  int k = blockIdx.y, b = blockIdx.z;
  int tid = threadIdx.x, lane = tid & 63, wv = tid >> 6;
  int dg = lane >> 4, ng = lane & 15;
  int qp = (lane >> 2) & 3;
  int wd = wv * 4 + dg;
  int gd = k * DI_ + dblk * 32 + wd;
  v2f a2p[2], h2[2];
  #pragma unroll
  for (int j = 0; j < 2; ++j) {
    a2p[j].x = -__expf(A_logs[(size_t)gd * N_ + ng * 4 + 2 * j]) * 1.44269504f;
    a2p[j].y = -__expf(A_logs[(size_t)gd * N_ + ng * 4 + 2 * j + 1]) * 1.44269504f;
    h2[j].x = 0.f; h2[j].y = 0.f;
  }

  __shared__ float Bsh[2][CH][64];
  __shared__ float Csh[2][CH][64];
  __shared__ float DLU[2][32][DLP];
  __shared__ float yq[CH][32][YQP];
  __shared__ float dsh[32];

  const size_t spB = (size_t)b * L_ * 384 + 128 + k * 64;  // bf16 elems
  const size_t csB = (size_t)b * L_ * 256 + k * 64;        // bf16 elems
  const size_t dlB = ((size_t)(b * 4 + k) * L_) * DI_ + dblk * 32;
  const size_t xaB = (size_t)b * L_ * DI_ + dblk * 32;

  if (tid < 32) dsh[tid] = Ds[k * DI_ + dblk * 32 + tid];

  int liS = tid >> 5, js = tid & 31;
  int liE = tid >> 5, dd = tid & 31;
  auto posf = [&](int l) {
    int lr = 1023 - l;
    return (k == 0) ? l
         : (k == 1) ? ((l & 31) * 32 + (l >> 5))
         : (k == 2) ? lr
                    : ((lr & 31) * 32 + (lr >> 5));
  };

  // stage chunk 0 (bf16 -> f32 conversion at staging)
  {
    float2 fB = bfp2f(*(const unsigned int*)(sp + spB + (size_t)liS * 384 + js * 2));
    float2 fC = bfp2f(*(const unsigned int*)(Cs + csB + (size_t)liS * 256 + js * 2));
    *(float2*)&Bsh[0][liS][js * 2] = fB;
    *(float2*)&Csh[0][liS][js * 2] = fC;
    float2 p;
    p.x = bf2f(dltb[dlB + (size_t)liS * DI_ + js]);
    p.y = bf2f(xa[xaB + (size_t)posf(liS) * DI_ + js]);
    *(float2*)&DLU[0][js][liS * 2] = p;
  }
  __syncthreads();

  int cur = 0;
  for (int c = 0; c < NCH; ++c) {
    unsigned int pB, pC;
    unsigned short pD, pU;
    if (c < NCH - 1) {
      int lb = (c + 1) * CH + liS;
      pB = *(const unsigned int*)(sp + spB + (size_t)lb * 384 + js * 2);
      pC = *(const unsigned int*)(Cs + csB + (size_t)lb * 256 + js * 2);
      pD = dltb[dlB + (size_t)lb * DI_ + js];
      pU = xa[xaB + (size_t)posf(lb) * DI_ + js];
    }
    #pragma unroll
    for (int li2 = 0; li2 < CH; li2 += 2) {
      f32x4 duq = *(const f32x4*)&DLU[cur][wd][li2 * 2];
      #pragma unroll
      for (int s = 0; s < 2; ++s) {
        int li = li2 + s;
        float dlt = s ? duq[2] : duq[0];
        float u   = s ? duq[3] : duq[1];
        float du = dlt * u;
        f32x4 bq = *(const f32x4*)&Bsh[cur][li][ng * 4];
        f32x4 cq = *(const f32x4*)&Csh[cur][li][ng * 4];
        v2f b01 = __builtin_shufflevector(bq, bq, 0, 1);
        v2f b23 = __builtin_shufflevector(bq, bq, 2, 3);
        v2f c01 = __builtin_shufflevector(cq, cq, 0, 1);
        v2f c23 = __builtin_shufflevector(cq, cq, 2, 3);
        v2f dlt2; dlt2.x = dlt; dlt2.y = dlt;
        v2f du2;  du2.x = du;  du2.y = du;
        v2f arg0 = dlt2 * a2p[0];
        v2f arg1 = dlt2 * a2p[1];
        v2f e0, e1;
        e0.x = __builtin_amdgcn_exp2f(arg0.x);
        e0.y = __builtin_amdgcn_exp2f(arg0.y);
        e1.x = __builtin_amdgcn_exp2f(arg1.x);
        e1.y = __builtin_amdgcn_exp2f(arg1.y);
        h2[0] = e0 * h2[0] + du2 * b01;
        h2[1] = e1 * h2[1] + du2 * b23;
        v2f yv = h2[0] * c01 + h2[1] * c23;
        float yp = yv.x + yv.y;
        yp = dpp_add<0xB1>(yp);   // quad xor1
        yp = dpp_add<0x4E>(yp);   // quad xor2 -> 16-n quad partial
        yq[li][wd][qp] = yp;      // 4 quad lanes same value/addr (benign)
      }
    }
    __syncthreads();  // yq complete; DLU[cur] still valid
    {  // epilogue: one y output per thread
      float2 q01 = *(const float2*)&yq[liE][dd][0];
      float2 q23 = *(const float2*)&yq[liE][dd][2];
      float y = (q01.x + q01.y) + (q23.x + q23.y);
      float u = DLU[cur][dd][liE * 2 + 1];
      y = fmaf(u, dsh[dd], y);
      ybuf[dlB + (size_t)(c * CH + liE) * DI_ + dd] = f2bf(y);
    }
    if (c < NCH - 1) {
      int nxt = cur ^ 1;
      *(float2*)&Bsh[nxt][liS][js * 2] = bfp2f(pB);
      *(float2*)&Csh[nxt][liS][js * 2] = bfp2f(pC);
      float2 p; p.x = bf2f(pD); p.y = bf2f(pU);
      *(float2*)&DLU[nxt][js][liS * 2] = p;
    }
    __syncthreads();  // staging visible; yq free for next chunk
    cur ^= 1;
  }
}

// ---------------- fuse: ygz = (sum_k yk) * z  (yk bf16, z bf16) -> bf16 ----------------
__global__ __launch_bounds__(256) void fuse_ygz(
    const unsigned short* __restrict__ yk, const unsigned short* __restrict__ xz,
    unsigned short* __restrict__ ygz) {
  size_t i = ((size_t)blockIdx.x * 256 + threadIdx.x) * 8;
  size_t b = i >> 20, ld = i & ((1u << 20) - 1);
  float acc[8] = {};
  #pragma unroll
  for (int k = 0; k < 4; ++k) {
    uint4 v = *(const uint4*)(yk + ((size_t)(b * 4 + k) << 20) + ld);
    unsigned int w[4] = {v.x, v.y, v.z, v.w};
    #pragma unroll
    for (int t = 0; t < 4; ++t) {
      acc[t * 2 + 0] += __builtin_bit_cast(float, w[t] << 16);
      acc[t * 2 + 1] += __builtin_bit_cast(float, w[t] & 0xFFFF0000u);
    }
  }
  uint4 zv = *(const uint4*)(xz + (i >> 10) * (2 * DI_) + DI_ + (i & (DI_ - 1)));
  unsigned int zw[4] = {zv.x, zv.y, zv.z, zv.w};
  float z[8];
  #pragma unroll
  for (int t = 0; t < 4; ++t) {
    z[t * 2 + 0] = __builtin_bit_cast(float, zw[t] << 16);
    z[t * 2 + 1] = __builtin_bit_cast(float, zw[t] & 0xFFFF0000u);
  }
  uint4 o;
  o.x = (unsigned int)f2bf(acc[0] * z[0]) | ((unsigned int)f2bf(acc[1] * z[1]) << 16);
  o.y = (unsigned int)f2bf(acc[2] * z[2]) | ((unsigned int)f2bf(acc[3] * z[3]) << 16);
  o.z = (unsigned int)f2bf(acc[4] * z[4]) | ((unsigned int)f2bf(acc[5] * z[5]) << 16);
  o.w = (unsigned int)f2bf(acc[6] * z[6]) | ((unsigned int)f2bf(acc[7] * z[7]) << 16);
  *(uint4*)(ygz + i) = o;
}

// ---------------- host ----------------
extern "C" void kernel_launch(void* const* d_in, const int* in_sizes, int n_in,
                              void* d_out, int out_size, void* d_ws, size_t ws_size,
                              hipStream_t stream) {
  (void)in_sizes; (void)n_in; (void)out_size; (void)ws_size;
  const float* content   = (const float*)d_in[0];
  const float* style     = (const float*)d_in[1];
  const float* norm1_w   = (const float*)d_in[2];
  const float* norm1_b   = (const float*)d_in[3];
  const float* in_proj_w = (const float*)d_in[4];
  const float* conv_w    = (const float*)d_in[5];
  const float* conv_b    = (const float*)d_in[6];
  const float* style_proj_w   = (const float*)d_in[7];
  const float* content_proj_w = (const float*)d_in[8];
  const float* dtw       = (const float*)d_in[9];
  const float* dtb       = (const float*)d_in[10];
  const float* A_logs    = (const float*)d_in[11];
  const float* Ds        = (const float*)d_in[12];
  const float* out_proj_w = (const float*)d_in[13];
  const float* norm2_w   = (const float*)d_in[14];
  const float* norm2_b   = (const float*)d_in[15];
  const float* mlp_w1    = (const float*)d_in[16];
  const float* mlp_b1    = (const float*)d_in[17];
  const float* mlp_w2    = (const float*)d_in[18];
  const float* mlp_b2    = (const float*)d_in[19];
  float* out = (float*)d_out;

  float* ws = (float*)d_ws;
  const size_t ROWS = (size_t)B_ * L_;
  const size_t SCAN_ELEMS = (size_t)B_ * K_ * L_ * DI_;
  size_t o = 0;
  unsigned short* cn  = (unsigned short*)(ws + o); o += ROWS * HID_ / 2;
  unsigned short* sn  = (unsigned short*)(ws + o); o += ROWS * HID_ / 2;
  unsigned short* xn  = (unsigned short*)(ws + o); o += ROWS * HID_ / 2;
  unsigned short* xz  = (unsigned short*)(ws + o); o += ROWS * 2 * DI_ / 2;
  unsigned short* sp  = (unsigned short*)(ws + o); o += ROWS * 384 / 2;
  unsigned short* xa  = (unsigned short*)(ws + o); o += ROWS * DI_ / 2;
  unsigned short* csb = (unsigned short*)(ws + o); o += ROWS * 256 / 2;
  float* x1    = ws + o; o += ROWS * HID_;
  unsigned short* dltb = (unsigned short*)(ws + o); o += SCAN_ELEMS / 2;
  unsigned short* ybuf = (unsigned short*)(ws + o); o += SCAN_ELEMS / 2;
  unsigned short* ygz  = (unsigned short*)(ws + o); o += ROWS * DI_ / 2;
  unsigned short* wt = (unsigned short*)(ws + o);
  unsigned short* inpT = wt;
  unsigned short* styT = inpT + 2048 * 512;
  unsigned short* conT = styT + 384 * 512;
  unsigned short* outT = conT + 256 * 1024;
  unsigned short* w1T  = outT + 512 * 1024;
  unsigned short* w2T  = w1T + 2048 * 512;
  unsigned short* dtwB = w2T + 512 * 2048;
  unsigned short* hmid = ybuf;

  transpose_all<<<4032, 256, 0, stream>>>(
      in_proj_w, style_proj_w, content_proj_w, out_proj_w, mlp_w1, mlp_w2,
      inpT, styT, conT, outT, w1T, w2T);
  cast_bf<<<(K_ * DI_ * R_) / 1024, 256, 0, stream>>>(dtw, dtwB);

  ln_kernel<<<dim3(ROWS / 4, 2), 256, 0, stream>>>(content, cn, style, sn, norm1_w, norm1_b);

  gemm_kernel<0, 1><<<dim3(2048 / BN, ROWS / BM), 256, 0, stream>>>(
      cn, inpT, xz, ROWS, 2048, 512, nullptr, nullptr);
  gemm64_kernel<0, 1><<<dim3(384 / BN, ROWS / 64), 256, 0, stream>>>(
      sn, styT, sp, ROWS, 384, 512, nullptr, nullptr);
  conv_kernel<<<(ROWS * DI_) / 256, 256, 0, stream>>>(xz, conv_w, conv_b, xa);
  gemm64_kernel<0, 1><<<dim3(256 / BN, ROWS / 64), 256, 0, stream>>>(
      xa, conT, csb, ROWS, 256, 1024, nullptr, nullptr);
  dtgemm_kernel<<<dim3(DI_ / 128, ROWS / 64, K_), 256, 0, stream>>>(sp, dtwB, dtb, dltb);
  scan_kernel<<<dim3(DI_ / 32, K_, B_), 512, 0, stream>>>(
      ybuf, xa, sp, csb, dltb, A_logs, Ds);
  fuse_ygz<<<(ROWS * DI_) / (256 * 8), 256, 0, stream>>>(ybuf, xz, ygz);
  gemm64_kernel<1, 0><<<dim3(512 / BN, ROWS / 64), 256, 0, stream>>>(
      ygz, outT, x1, ROWS, 512, 1024, nullptr, content);
  ln_kernel<<<dim3(ROWS / 4, 1), 256, 0, stream>>>(x1, xn, nullptr, nullptr, norm2_w, norm2_b);
  gemm_kernel<2, 1><<<dim3(2048 / BN, ROWS / BM), 256, 0, stream>>>(
      xn, w1T, hmid, ROWS, 2048, 512, mlp_b1, nullptr);
  gemm64_kernel<3, 0><<<dim3(512 / BN, ROWS / 64), 256, 0, stream>>>(
      hmid, w2T, out, ROWS, 512, 2048, mlp_b2, x1);
}

// Round 15
// 426.531 us; speedup vs baseline: 1.1369x; 1.0438x over previous
//
#include <hip/hip_runtime.h>

// ---------------- constants ----------------
#define B_ 4
#define Hh_ 32
#define Ww_ 32
#define L_ 1024
#define HID_ 512
#define DI_ 1024
#define N_ 64
#define R_ 32
#define K_ 4
#define MLP_ 2048

typedef __bf16 bf16x8 __attribute__((ext_vector_type(8)));
typedef float f32x4 __attribute__((ext_vector_type(4)));
typedef float v2f __attribute__((ext_vector_type(2)));

__device__ __forceinline__ unsigned short f2bf(float f) {
  unsigned int u = __builtin_bit_cast(unsigned int, f);
  return (unsigned short)((u + 0x7FFFu + ((u >> 16) & 1u)) >> 16);
}
__device__ __forceinline__ float bf2f(unsigned short h) {
  return __builtin_bit_cast(float, (unsigned int)h << 16);
}
__device__ __forceinline__ float2 bfp2f(unsigned int u) {
  float2 r;
  r.x = __builtin_bit_cast(float, u << 16);
  r.y = __builtin_bit_cast(float, u & 0xFFFF0000u);
  return r;
}

// async global->LDS, 16B per lane; lds base must be wave-uniform
__device__ __forceinline__ void gload16(const unsigned short* g, unsigned short* l) {
  __builtin_amdgcn_global_load_lds(
      (const __attribute__((address_space(1))) unsigned int*)g,
      (__attribute__((address_space(3))) unsigned int*)l, 16, 0, 0);
}

// DPP add: x + x[perm(lane)] on the VALU pipe (no DS traffic)
template <int CTRL>
__device__ __forceinline__ float dpp_add(float x) {
  int i = __builtin_bit_cast(int, x);
  int j = __builtin_amdgcn_update_dpp(i, i, CTRL, 0xF, 0xF, false);
  return x + __builtin_bit_cast(float, j);
}

// ---------------- all 6 weight transposes in ONE launch ----------------
__global__ __launch_bounds__(256) void transpose_all(
    const float* __restrict__ s0, const float* __restrict__ s1,
    const float* __restrict__ s2, const float* __restrict__ s3,
    const float* __restrict__ s4, const float* __restrict__ s5,
    unsigned short* __restrict__ t0, unsigned short* __restrict__ t1,
    unsigned short* __restrict__ t2, unsigned short* __restrict__ t3,
    unsigned short* __restrict__ t4, unsigned short* __restrict__ t5) {
  __shared__ float t[32][33];
  int bid = blockIdx.x;
  const float* src; unsigned short* dst; int K, N, bx, by;
  if (bid < 1024)      { src = s0; dst = t0; K = 512;  N = 2048; int r = bid;        bx = r & 63; by = r >> 6; }
  else if (bid < 1216) { src = s1; dst = t1; K = 512;  N = 384;  int r = bid - 1024; bx = r % 12; by = r / 12; }
  else if (bid < 1472) { src = s2; dst = t2; K = 1024; N = 256;  int r = bid - 1216; bx = r & 7;  by = r >> 3; }
  else if (bid < 1984) { src = s3; dst = t3; K = 1024; N = 512;  int r = bid - 1472; bx = r & 15; by = r >> 4; }
  else if (bid < 3008) { src = s4; dst = t4; K = 512;  N = 2048; int r = bid - 1984; bx = r & 63; by = r >> 6; }
  else                 { src = s5; dst = t5; K = 2048; N = 512;  int r = bid - 3008; bx = r & 15; by = r >> 4; }
  int nb = bx * 32, kb = by * 32;
  int tx = threadIdx.x & 31, ty = threadIdx.x >> 5;
  for (int r = ty; r < 32; r += 8) t[r][tx] = src[(size_t)(kb + r) * N + nb + tx];
  __syncthreads();
  for (int r = ty; r < 32; r += 8) dst[(size_t)(nb + r) * K + kb + tx] = f2bf(t[tx][r]);
}

// ---------------- cast f32 -> bf16 (for dtw) ----------------
__global__ __launch_bounds__(256) void cast_bf(
    const float* __restrict__ src, unsigned short* __restrict__ dst) {
  int i = (blockIdx.x * 256 + threadIdx.x) * 4;
  float4 v = *(const float4*)(src + i);
  ushort4 o = {f2bf(v.x), f2bf(v.y), f2bf(v.z), f2bf(v.w)};
  *(ushort4*)(dst + i) = o;
}

// ---------------- conv weight transpose: cw (DI,9) -> cwT (9,DI) ----------------
__global__ __launch_bounds__(256) void prep_cw(
    const float* __restrict__ cw, float* __restrict__ cwT) {
  int i = blockIdx.x * 256 + threadIdx.x;
  if (i < DI_ * 9) {
    int d = i / 9, t = i % 9;
    cwT[t * DI_ + d] = cw[i];
  }
}

// ---------------- LayerNorm over 512, wave per row; writes bf16 ----------------
__global__ __launch_bounds__(256) void ln_kernel(
    const float* __restrict__ in0, unsigned short* __restrict__ out0,
    const float* __restrict__ in1, unsigned short* __restrict__ out1,
    const float* __restrict__ w, const float* __restrict__ bb) {
  const float* in = blockIdx.y ? in1 : in0;
  unsigned short* out = blockIdx.y ? out1 : out0;
  int row = blockIdx.x * 4 + (threadIdx.x >> 6);
  int lane = threadIdx.x & 63;
  const float* p = in + (size_t)row * HID_;
  float4 v0 = *(const float4*)(p + lane * 4);
  float4 v1 = *(const float4*)(p + 256 + lane * 4);
  float s = v0.x + v0.y + v0.z + v0.w + v1.x + v1.y + v1.z + v1.w;
  float q = v0.x * v0.x + v0.y * v0.y + v0.z * v0.z + v0.w * v0.w +
            v1.x * v1.x + v1.y * v1.y + v1.z * v1.z + v1.w * v1.w;
  #pragma unroll
  for (int m = 1; m < 64; m <<= 1) { s += __shfl_xor(s, m, 64); q += __shfl_xor(q, m, 64); }
  float mean = s * (1.f / 512.f);
  float var = q * (1.f / 512.f) - mean * mean;
  float rstd = rsqrtf(var + 1e-5f);
  float4 w0 = *(const float4*)(w + lane * 4);
  float4 w1 = *(const float4*)(w + 256 + lane * 4);
  float4 b0 = *(const float4*)(bb + lane * 4);
  float4 b1 = *(const float4*)(bb + 256 + lane * 4);
  unsigned short* o = out + (size_t)row * HID_;
  ushort4 r0, r1;
  r0.x = f2bf((v0.x - mean) * rstd * w0.x + b0.x);
  r0.y = f2bf((v0.y - mean) * rstd * w0.y + b0.y);
  r0.z = f2bf((v0.z - mean) * rstd * w0.z + b0.z);
  r0.w = f2bf((v0.w - mean) * rstd * w0.w + b0.w);
  r1.x = f2bf((v1.x - mean) * rstd * w1.x + b1.x);
  r1.y = f2bf((v1.y - mean) * rstd * w1.y + b1.y);
  r1.z = f2bf((v1.z - mean) * rstd * w1.z + b1.z);
  r1.w = f2bf((v1.w - mean) * rstd * w1.w + b1.w);
  *(ushort4*)(o + lane * 4) = r0;
  *(ushort4*)(o + 256 + lane * 4) = r1;
}

// ---------------- MFMA GEMM 128x128, BK=64, global_load_lds + XOR swizzle ----------------
#define BM 128
#define BN 128
#define BK 64

template <int EPI, int OUTBF>
__global__ __launch_bounds__(256) void gemm_kernel(
    const unsigned short* __restrict__ A, const unsigned short* __restrict__ BT,
    void* __restrict__ Cv, int M, int N, int K,
    const float* __restrict__ bias, const float* __restrict__ resid) {
  __shared__ __align__(16) unsigned short As[BM * BK];
  __shared__ __align__(16) unsigned short Bs[BN * BK];
  int tid = threadIdx.x;
  int lane = tid & 63, wv = tid >> 6;
  int wm = wv >> 1, wn = wv & 1;
  int nwg = gridDim.x * gridDim.y;
  int flat = blockIdx.y * gridDim.x + blockIdx.x;
  int swz = (flat & 7) * (nwg >> 3) + (flat >> 3);
  int bx = swz % gridDim.x, by = swz / gridDim.x;
  int m0 = by * BM, n0 = bx * BN;
  f32x4 acc[4][4] = {};
  int rowblk = lane >> 3;
  int sblk = (lane & 7) ^ rowblk;
  int rA = wm * 64 + (lane & 15);
  int rB = wn * 64 + (lane & 15);
  for (int k0 = 0; k0 < K; k0 += BK) {
    __syncthreads();
    #pragma unroll
    for (int it = 0; it < 4; ++it) {
      int r0 = wv * 32 + it * 8;
      gload16(A + (size_t)(m0 + r0 + rowblk) * K + k0 + sblk * 8, &As[r0 * BK]);
      gload16(BT + (size_t)(n0 + r0 + rowblk) * K + k0 + sblk * 8, &Bs[r0 * BK]);
    }
    __syncthreads();
    #pragma unroll
    for (int kx = 0; kx < 2; ++kx) {
      int bidx = (lane >> 4) + kx * 4;
      bf16x8 fa[4], fb[4];
      #pragma unroll
      for (int i = 0; i < 4; ++i) {
        int ra = rA + i * 16;
        int rb = rB + i * 16;
        fa[i] = *(const bf16x8*)&As[ra * BK + ((bidx ^ (ra & 7)) << 3)];
        fb[i] = *(const bf16x8*)&Bs[rb * BK + ((bidx ^ (rb & 7)) << 3)];
      }
      #pragma unroll
      for (int i = 0; i < 4; ++i)
        #pragma unroll
        for (int j = 0; j < 4; ++j)
          acc[i][j] = __builtin_amdgcn_mfma_f32_16x16x32_bf16(fa[i], fb[j], acc[i][j], 0, 0, 0);
    }
  }
  int crow0 = m0 + wm * 64 + (lane >> 4) * 4, ccol0 = n0 + wn * 64 + (lane & 15);
  #pragma unroll
  for (int i = 0; i < 4; ++i) {
    #pragma unroll
    for (int j = 0; j < 4; ++j) {
      int col = ccol0 + j * 16;
      #pragma unroll
      for (int r = 0; r < 4; ++r) {
        int row = crow0 + i * 16 + r;
        float v = acc[i][j][r];
        if (EPI == 1) v += resid[(size_t)row * N + col];
        if (EPI == 2) { v += bias[col]; v = 0.5f * v * (1.f + erff(v * 0.70710678f)); }
        if (EPI == 3) v += bias[col] + resid[(size_t)row * N + col];
        if (OUTBF) ((unsigned short*)Cv)[(size_t)row * N + col] = f2bf(v);
        else       ((float*)Cv)[(size_t)row * N + col] = v;
      }
    }
  }
}

// ---------------- MFMA GEMM 64x128, BK=64, global_load_lds + XOR swizzle ----------------
template <int EPI, int OUTBF>
__global__ __launch_bounds__(256) void gemm64_kernel(
    const unsigned short* __restrict__ A, const unsigned short* __restrict__ BT,
    void* __restrict__ Cv, int M, int N, int K,
    const float* __restrict__ bias, const float* __restrict__ resid) {
  __shared__ __align__(16) unsigned short As[64 * BK];
  __shared__ __align__(16) unsigned short Bs[128 * BK];
  int tid = threadIdx.x;
  int lane = tid & 63, wv = tid >> 6;
  int wm = wv >> 1, wn = wv & 1;
  int nwg = gridDim.x * gridDim.y;
  int flat = blockIdx.y * gridDim.x + blockIdx.x;
  int swz = (flat & 7) * (nwg >> 3) + (flat >> 3);
  int bx = swz % gridDim.x, by = swz / gridDim.x;
  int m0 = by * 64, n0 = bx * BN;
  f32x4 acc[2][4] = {};
  int rowblk = lane >> 3;
  int sblk = (lane & 7) ^ rowblk;
  int rA = wm * 32 + (lane & 15);
  int rB = wn * 64 + (lane & 15);
  for (int k0 = 0; k0 < K; k0 += BK) {
    __syncthreads();
    #pragma unroll
    for (int it = 0; it < 2; ++it) {
      int r0 = wv * 16 + it * 8;
      gload16(A + (size_t)(m0 + r0 + rowblk) * K + k0 + sblk * 8, &As[r0 * BK]);
    }
    #pragma unroll
    for (int it = 0; it < 4; ++it) {
      int r0 = wv * 32 + it * 8;
      gload16(BT + (size_t)(n0 + r0 + rowblk) * K + k0 + sblk * 8, &Bs[r0 * BK]);
    }
    __syncthreads();
    #pragma unroll
    for (int kx = 0; kx < 2; ++kx) {
      int bidx = (lane >> 4) + kx * 4;
      bf16x8 fa[2], fb[4];
      #pragma unroll
      for (int i = 0; i < 2; ++i) {
        int ra = rA + i * 16;
        fa[i] = *(const bf16x8*)&As[ra * BK + ((bidx ^ (ra & 7)) << 3)];
      }
      #pragma unroll
      for (int j = 0; j < 4; ++j) {
        int rb = rB + j * 16;
        fb[j] = *(const bf16x8*)&Bs[rb * BK + ((bidx ^ (rb & 7)) << 3)];
      }
      #pragma unroll
      for (int i = 0; i < 2; ++i)
        #pragma unroll
        for (int j = 0; j < 4; ++j)
          acc[i][j] = __builtin_amdgcn_mfma_f32_16x16x32_bf16(fa[i], fb[j], acc[i][j], 0, 0, 0);
    }
  }
  int crow0 = m0 + wm * 32 + (lane >> 4) * 4, ccol0 = n0 + wn * 64 + (lane & 15);
  #pragma unroll
  for (int i = 0; i < 2; ++i) {
    #pragma unroll
    for (int j = 0; j < 4; ++j) {
      int col = ccol0 + j * 16;
      #pragma unroll
      for (int r = 0; r < 4; ++r) {
        int row = crow0 + i * 16 + r;
        float v = acc[i][j][r];
        if (EPI == 1) v += resid[(size_t)row * N + col];
        if (EPI == 2) { v += bias[col]; v = 0.5f * v * (1.f + erff(v * 0.70710678f)); }
        if (EPI == 3) v += bias[col] + resid[(size_t)row * N + col];
        if (OUTBF) ((unsigned short*)Cv)[(size_t)row * N + col] = f2bf(v);
        else       ((float*)Cv)[(size_t)row * N + col] = v;
      }
    }
  }
}

// ---------------- delta GEMM: softplus(spRank @ dtw^T + dtb) -> bf16 ----------------
__global__ __launch_bounds__(256) void dtgemm_kernel(
    const unsigned short* __restrict__ sp, const unsigned short* __restrict__ dtwB,
    const float* __restrict__ dtb, unsigned short* __restrict__ delta) {
  int kq = blockIdx.z;
  int m0 = blockIdx.y * 64, n0 = blockIdx.x * 128;
  __shared__ __align__(16) unsigned short As[64 * 32];
  __shared__ __align__(16) unsigned short Bs[128 * 32];
  int tid = threadIdx.x, lane = tid & 63, wv = tid >> 6;
  int wm = wv >> 1, wn = wv & 1;
  {
    int r = tid >> 2, c = (tid & 3) * 8;
    *(uint4*)&As[r * 32 + c] = *(const uint4*)(sp + (size_t)(m0 + r) * 384 + kq * 32 + c);
  }
  {
    int r = tid >> 1, c = (tid & 1) * 16;
    const unsigned short* p = dtwB + (size_t)(kq * DI_ + n0 + r) * 32 + c;
    *(uint4*)&Bs[r * 32 + c] = *(const uint4*)(p);
    *(uint4*)&Bs[r * 32 + c + 8] = *(const uint4*)(p + 8);
  }
  __syncthreads();
  int kk = (lane >> 4) * 8;
  int rA = wm * 32 + (lane & 15);
  int rB = wn * 64 + (lane & 15);
  f32x4 acc[2][4] = {};
  bf16x8 fa[2], fb[4];
  #pragma unroll
  for (int i = 0; i < 2; ++i) fa[i] = *(const bf16x8*)&As[(rA + i * 16) * 32 + kk];
  #pragma unroll
  for (int j = 0; j < 4; ++j) fb[j] = *(const bf16x8*)&Bs[(rB + j * 16) * 32 + kk];
  #pragma unroll
  for (int i = 0; i < 2; ++i)
    #pragma unroll
    for (int j = 0; j < 4; ++j)
      acc[i][j] = __builtin_amdgcn_mfma_f32_16x16x32_bf16(fa[i], fb[j], acc[i][j], 0, 0, 0);
  int crow0 = m0 + wm * 32 + (lane >> 4) * 4, ccol0 = n0 + wn * 64 + (lane & 15);
  #pragma unroll
  for (int i = 0; i < 2; ++i) {
    #pragma unroll
    for (int j = 0; j < 4; ++j) {
      int col = ccol0 + j * 16;
      float bias = dtb[kq * DI_ + col];
      #pragma unroll
      for (int r = 0; r < 4; ++r) {
        int row = crow0 + i * 16 + r;
        float v = acc[i][j][r] + bias;
        v = (v > 15.f) ? v : log1pf(__expf(v));
        int bb = row >> 10, l = row & 1023;
        delta[(((size_t)(bb * 4 + kq)) << 20) + ((size_t)l << 10) + col] = f2bf(v);
      }
    }
  }
}

// ---------------- depthwise 3x3 conv + bias + SiLU; vectorized 8 d/thread ----------------
__global__ __launch_bounds__(256) void conv_kernel(
    const unsigned short* __restrict__ xz, const float* __restrict__ cwT,
    const float* __restrict__ cb, unsigned short* __restrict__ xa) {
  int idx = blockIdx.x * 256 + threadIdx.x;   // B*L*DI/8 = 524288 threads
  int d0 = (idx & 127) * 8;
  int l = (idx >> 7) & (L_ - 1);
  int b = idx >> 17;
  int hh = l >> 5, ww = l & 31;
  float acc[8];
  {
    float4 c0 = *(const float4*)(cb + d0);
    float4 c1 = *(const float4*)(cb + d0 + 4);
    acc[0] = c0.x; acc[1] = c0.y; acc[2] = c0.z; acc[3] = c0.w;
    acc[4] = c1.x; acc[5] = c1.y; acc[6] = c1.z; acc[7] = c1.w;
  }
  #pragma unroll
  for (int dh = -1; dh <= 1; ++dh) {
    int y = hh + dh;
    if ((unsigned)y >= 32u) continue;
    #pragma unroll
    for (int dw = -1; dw <= 1; ++dw) {
      int x = ww + dw;
      if ((unsigned)x >= 32u) continue;
      int tap = (dh + 1) * 3 + (dw + 1);
      uint4 v = *(const uint4*)(xz + ((size_t)b * L_ + y * 32 + x) * (2 * DI_) + d0);
      float4 w0 = *(const float4*)(cwT + tap * DI_ + d0);
      float4 w1 = *(const float4*)(cwT + tap * DI_ + d0 + 4);
      unsigned int wd[4] = {v.x, v.y, v.z, v.w};
      float xv[8];
      #pragma unroll
      for (int t = 0; t < 4; ++t) {
        xv[t * 2 + 0] = __builtin_bit_cast(float, wd[t] << 16);
        xv[t * 2 + 1] = __builtin_bit_cast(float, wd[t] & 0xFFFF0000u);
      }
      acc[0] = fmaf(xv[0], w0.x, acc[0]);
      acc[1] = fmaf(xv[1], w0.y, acc[1]);
      acc[2] = fmaf(xv[2], w0.z, acc[2]);
      acc[3] = fmaf(xv[3], w0.w, acc[3]);
      acc[4] = fmaf(xv[4], w1.x, acc[4]);
      acc[5] = fmaf(xv[5], w1.y, acc[5]);
      acc[6] = fmaf(xv[6], w1.z, acc[6]);
      acc[7] = fmaf(xv[7], w1.w, acc[7]);
    }
  }
  uint4 o;
  float s0 = acc[0] / (1.f + __expf(-acc[0]));
  float s1 = acc[1] / (1.f + __expf(-acc[1]));
  float s2 = acc[2] / (1.f + __expf(-acc[2]));
  float s3 = acc[3] / (1.f + __expf(-acc[3]));
  float s4 = acc[4] / (1.f + __expf(-acc[4]));
  float s5 = acc[5] / (1.f + __expf(-acc[5]));
  float s6 = acc[6] / (1.f + __expf(-acc[6]));
  float s7 = acc[7] / (1.f + __expf(-acc[7]));
  o.x = (unsigned int)f2bf(s0) | ((unsigned int)f2bf(s1) << 16);
  o.y = (unsigned int)f2bf(s2) | ((unsigned int)f2bf(s3) << 16);
  o.z = (unsigned int)f2bf(s4) | ((unsigned int)f2bf(s5) << 16);
  o.w = (unsigned int)f2bf(s6) | ((unsigned int)f2bf(s7) << 16);
  *(uint4*)(xa + ((size_t)b * L_ + l) * DI_ + d0) = o;
}

// ---------------- selective scan: r11 structure (f32 LDS B/C, quad-partial reduce) ----------------
#define CH 16
#define NCH (L_ / CH)
#define DLP 36
#define YQP 6
__global__ __launch_bounds__(512) void scan_kernel(
    unsigned short* __restrict__ ybuf, const unsigned short* __restrict__ xa,
    const unsigned short* __restrict__ sp, const unsigned short* __restrict__ Cs,
    const unsigned short* __restrict__ dltb,
    const float* __restrict__ A_logs, const float* __restrict__ Ds) {
  int dblk = blockIdx.x;
  int k = blockIdx.y, b = blockIdx.z;
  int tid = threadIdx.x, lane = tid & 63, wv = tid >> 6;
  int dg = lane >> 4, ng = lane & 15;
  int qp = (lane >> 2) & 3;
  int wd = wv * 4 + dg;
  int gd = k * DI_ + dblk * 32 + wd;
  v2f a2p[2], h2[2];
  #pragma unroll
  for (int j = 0; j < 2; ++j) {
    a2p[j].x = -__expf(A_logs[(size_t)gd * N_ + ng * 4 + 2 * j]) * 1.44269504f;
    a2p[j].y = -__expf(A_logs[(size_t)gd * N_ + ng * 4 + 2 * j + 1]) * 1.44269504f;
    h2[j].x = 0.f; h2[j].y = 0.f;
  }

  __shared__ float Bsh[2][CH][64];
  __shared__ float Csh[2][CH][64];
  __shared__ float DLU[2][32][DLP];
  __shared__ float yq[CH][32][YQP];
  __shared__ float dsh[32];

  const size_t spB = (size_t)b * L_ * 384 + 128 + k * 64;
  const size_t csB = (size_t)b * L_ * 256 + k * 64;
  const size_t dlB = ((size_t)(b * 4 + k) * L_) * DI_ + dblk * 32;
  const size_t xaB = (size_t)b * L_ * DI_ + dblk * 32;

  if (tid < 32) dsh[tid] = Ds[k * DI_ + dblk * 32 + tid];

  int liS = tid >> 5, js = tid & 31;
  int liE = tid >> 5, dd = tid & 31;
  auto posf = [&](int l) {
    int lr = 1023 - l;
    return (k == 0) ? l
         : (k == 1) ? ((l & 31) * 32 + (l >> 5))
         : (k == 2) ? lr
                    : ((lr & 31) * 32 + (lr >> 5));
  };

  {
    float2 fB = bfp2f(*(const unsigned int*)(sp + spB + (size_t)liS * 384 + js * 2));
    float2 fC = bfp2f(*(const unsigned int*)(Cs + csB + (size_t)liS * 256 + js * 2));
    *(float2*)&Bsh[0][liS][js * 2] = fB;
    *(float2*)&Csh[0][liS][js * 2] = fC;
    float2 p;
    p.x = bf2f(dltb[dlB + (size_t)liS * DI_ + js]);
    p.y = bf2f(xa[xaB + (size_t)posf(liS) * DI_ + js]);
    *(float2*)&DLU[0][js][liS * 2] = p;
  }
  __syncthreads();

  int cur = 0;
  for (int c = 0; c < NCH; ++c) {
    unsigned int pB, pC;
    unsigned short pD, pU;
    if (c < NCH - 1) {
      int lb = (c + 1) * CH + liS;
      pB = *(const unsigned int*)(sp + spB + (size_t)lb * 384 + js * 2);
      pC = *(const unsigned int*)(Cs + csB + (size_t)lb * 256 + js * 2);
      pD = dltb[dlB + (size_t)lb * DI_ + js];
      pU = xa[xaB + (size_t)posf(lb) * DI_ + js];
    }
    #pragma unroll
    for (int li2 = 0; li2 < CH; li2 += 2) {
      f32x4 duq = *(const f32x4*)&DLU[cur][wd][li2 * 2];
      #pragma unroll
      for (int s = 0; s < 2; ++s) {
        int li = li2 + s;
        float dlt = s ? duq[2] : duq[0];
        float u   = s ? duq[3] : duq[1];
        float du = dlt * u;
        f32x4 bq = *(const f32x4*)&Bsh[cur][li][ng * 4];
        f32x4 cq = *(const f32x4*)&Csh[cur][li][ng * 4];
        v2f b01 = __builtin_shufflevector(bq, bq, 0, 1);
        v2f b23 = __builtin_shufflevector(bq, bq, 2, 3);
        v2f c01 = __builtin_shufflevector(cq, cq, 0, 1);
        v2f c23 = __builtin_shufflevector(cq, cq, 2, 3);
        v2f dlt2; dlt2.x = dlt; dlt2.y = dlt;
        v2f du2;  du2.x = du;  du2.y = du;
        v2f arg0 = dlt2 * a2p[0];
        v2f arg1 = dlt2 * a2p[1];
        v2f e0, e1;
        e0.x = __builtin_amdgcn_exp2f(arg0.x);
        e0.y = __builtin_amdgcn_exp2f(arg0.y);
        e1.x = __builtin_amdgcn_exp2f(arg1.x);
        e1.y = __builtin_amdgcn_exp2f(arg1.y);
        h2[0] = e0 * h2[0] + du2 * b01;
        h2[1] = e1 * h2[1] + du2 * b23;
        v2f yv = h2[0] * c01 + h2[1] * c23;
        float yp = yv.x + yv.y;
        yp = dpp_add<0xB1>(yp);
        yp = dpp_add<0x4E>(yp);
        yq[li][wd][qp] = yp;
      }
    }
    __syncthreads();
    {
      float2 q01 = *(const float2*)&yq[liE][dd][0];
      float2 q23 = *(const float2*)&yq[liE][dd][2];
      float y = (q01.x + q01.y) + (q23.x + q23.y);
      float u = DLU[cur][dd][liE * 2 + 1];
      y = fmaf(u, dsh[dd], y);
      ybuf[dlB + (size_t)(c * CH + liE) * DI_ + dd] = f2bf(y);
    }
    if (c < NCH - 1) {
      int nxt = cur ^ 1;
      *(float2*)&Bsh[nxt][liS][js * 2] = bfp2f(pB);
      *(float2*)&Csh[nxt][liS][js * 2] = bfp2f(pC);
      float2 p; p.x = bf2f(pD); p.y = bf2f(pU);
      *(float2*)&DLU[nxt][js][liS * 2] = p;
    }
    __syncthreads();
    cur ^= 1;
  }
}

// ---------------- fuse: ygz = (sum_k yk) * z  (yk bf16, z bf16) -> bf16 ----------------
__global__ __launch_bounds__(256) void fuse_ygz(
    const unsigned short* __restrict__ yk, const unsigned short* __restrict__ xz,
    unsigned short* __restrict__ ygz) {
  size_t i = ((size_t)blockIdx.x * 256 + threadIdx.x) * 8;
  size_t b = i >> 20, ld = i & ((1u << 20) - 1);
  float acc[8] = {};
  #pragma unroll
  for (int k = 0; k < 4; ++k) {
    uint4 v = *(const uint4*)(yk + ((size_t)(b * 4 + k) << 20) + ld);
    unsigned int w[4] = {v.x, v.y, v.z, v.w};
    #pragma unroll
    for (int t = 0; t < 4; ++t) {
      acc[t * 2 + 0] += __builtin_bit_cast(float, w[t] << 16);
      acc[t * 2 + 1] += __builtin_bit_cast(float, w[t] & 0xFFFF0000u);
    }
  }
  uint4 zv = *(const uint4*)(xz + (i >> 10) * (2 * DI_) + DI_ + (i & (DI_ - 1)));
  unsigned int zw[4] = {zv.x, zv.y, zv.z, zv.w};
  float z[8];
  #pragma unroll
  for (int t = 0; t < 4; ++t) {
    z[t * 2 + 0] = __builtin_bit_cast(float, zw[t] << 16);
    z[t * 2 + 1] = __builtin_bit_cast(float, zw[t] & 0xFFFF0000u);
  }
  uint4 o;
  o.x = (unsigned int)f2bf(acc[0] * z[0]) | ((unsigned int)f2bf(acc[1] * z[1]) << 16);
  o.y = (unsigned int)f2bf(acc[2] * z[2]) | ((unsigned int)f2bf(acc[3] * z[3]) << 16);
  o.z = (unsigned int)f2bf(acc[4] * z[4]) | ((unsigned int)f2bf(acc[5] * z[5]) << 16);
  o.w = (unsigned int)f2bf(acc[6] * z[6]) | ((unsigned int)f2bf(acc[7] * z[7]) << 16);
  *(uint4*)(ygz + i) = o;
}

// ---------------- host ----------------
extern "C" void kernel_launch(void* const* d_in, const int* in_sizes, int n_in,
                              void* d_out, int out_size, void* d_ws, size_t ws_size,
                              hipStream_t stream) {
  (void)in_sizes; (void)n_in; (void)out_size; (void)ws_size;
  const float* content   = (const float*)d_in[0];
  const float* style     = (const float*)d_in[1];
  const float* norm1_w   = (const float*)d_in[2];
  const float* norm1_b   = (const float*)d_in[3];
  const float* in_proj_w = (const float*)d_in[4];
  const float* conv_w    = (const float*)d_in[5];
  const float* conv_b    = (const float*)d_in[6];
  const float* style_proj_w   = (const float*)d_in[7];
  const float* content_proj_w = (const float*)d_in[8];
  const float* dtw       = (const float*)d_in[9];
  const float* dtb       = (const float*)d_in[10];
  const float* A_logs    = (const float*)d_in[11];
  const float* Ds        = (const float*)d_in[12];
  const float* out_proj_w = (const float*)d_in[13];
  const float* norm2_w   = (const float*)d_in[14];
  const float* norm2_b   = (const float*)d_in[15];
  const float* mlp_w1    = (const float*)d_in[16];
  const float* mlp_b1    = (const float*)d_in[17];
  const float* mlp_w2    = (const float*)d_in[18];
  const float* mlp_b2    = (const float*)d_in[19];
  float* out = (float*)d_out;

  float* ws = (float*)d_ws;
  const size_t ROWS = (size_t)B_ * L_;
  const size_t SCAN_ELEMS = (size_t)B_ * K_ * L_ * DI_;
  size_t o = 0;
  unsigned short* cn  = (unsigned short*)(ws + o); o += ROWS * HID_ / 2;
  unsigned short* sn  = (unsigned short*)(ws + o); o += ROWS * HID_ / 2;
  unsigned short* xn  = (unsigned short*)(ws + o); o += ROWS * HID_ / 2;
  unsigned short* xz  = (unsigned short*)(ws + o); o += ROWS * 2 * DI_ / 2;
  unsigned short* sp  = (unsigned short*)(ws + o); o += ROWS * 384 / 2;
  unsigned short* xa  = (unsigned short*)(ws + o); o += ROWS * DI_ / 2;
  unsigned short* csb = (unsigned short*)(ws + o); o += ROWS * 256 / 2;
  float* x1    = ws + o; o += ROWS * HID_;
  unsigned short* dltb = (unsigned short*)(ws + o); o += SCAN_ELEMS / 2;
  unsigned short* ybuf = (unsigned short*)(ws + o); o += SCAN_ELEMS / 2;
  unsigned short* ygz  = (unsigned short*)(ws + o); o += ROWS * DI_ / 2;
  unsigned short* wt = (unsigned short*)(ws + o);
  unsigned short* inpT = wt;
  unsigned short* styT = inpT + 2048 * 512;
  unsigned short* conT = styT + 384 * 512;
  unsigned short* outT = conT + 256 * 1024;
  unsigned short* w1T  = outT + 512 * 1024;
  unsigned short* w2T  = w1T + 2048 * 512;
  unsigned short* dtwB = w2T + 512 * 2048;               // (K*DI,32) bf16
  float* cwT = (float*)(dtwB + (size_t)K_ * DI_ * R_);   // (9,DI) f32
  unsigned short* hmid = ybuf;

  transpose_all<<<4032, 256, 0, stream>>>(
      in_proj_w, style_proj_w, content_proj_w, out_proj_w, mlp_w1, mlp_w2,
      inpT, styT, conT, outT, w1T, w2T);
  cast_bf<<<(K_ * DI_ * R_) / 1024, 256, 0, stream>>>(dtw, dtwB);
  prep_cw<<<36, 256, 0, stream>>>(conv_w, cwT);

  ln_kernel<<<dim3(ROWS / 4, 2), 256, 0, stream>>>(content, cn, style, sn, norm1_w, norm1_b);

  gemm_kernel<0, 1><<<dim3(2048 / BN, ROWS / BM), 256, 0, stream>>>(
      cn, inpT, xz, ROWS, 2048, 512, nullptr, nullptr);
  gemm64_kernel<0, 1><<<dim3(384 / BN, ROWS / 64), 256, 0, stream>>>(
      sn, styT, sp, ROWS, 384, 512, nullptr, nullptr);
  conv_kernel<<<(ROWS * DI_) / (256 * 8), 256, 0, stream>>>(xz, cwT, conv_b, xa);
  gemm64_kernel<0, 1><<<dim3(256 / BN, ROWS / 64), 256, 0, stream>>>(
      xa, conT, csb, ROWS, 256, 1024, nullptr, nullptr);
  dtgemm_kernel<<<dim3(DI_ / 128, ROWS / 64, K_), 256, 0, stream>>>(sp, dtwB, dtb, dltb);
  scan_kernel<<<dim3(DI_ / 32, K_, B_), 512, 0, stream>>>(
      ybuf, xa, sp, csb, dltb, A_logs, Ds);
  fuse_ygz<<<(ROWS * DI_) / (256 * 8), 256, 0, stream>>>(ybuf, xz, ygz);
  gemm64_kernel<1, 0><<<dim3(512 / BN, ROWS / 64), 256, 0, stream>>>(
      ygz, outT, x1, ROWS, 512, 1024, nullptr, content);
  ln_kernel<<<dim3(ROWS / 4, 1), 256, 0, stream>>>(x1, xn, nullptr, nullptr, norm2_w, norm2_b);
  gemm_kernel<2, 1><<<dim3(2048 / BN, ROWS / BM), 256, 0, stream>>>(
      xn, w1T, hmid, ROWS, 2048, 512, mlp_b1, nullptr);
  gemm64_kernel<3, 0><<<dim3(512 / BN, ROWS / 64), 256, 0, stream>>>(
      hmid, w2T, out, ROWS, 512, 2048, mlp_b2, x1);
}

// Round 16
// 412.525 us; speedup vs baseline: 1.1755x; 1.0340x over previous
//
#include <hip/hip_runtime.h>

// ---------------- constants ----------------
#define B_ 4
#define Hh_ 32
#define Ww_ 32
#define L_ 1024
#define HID_ 512
#define DI_ 1024
#define N_ 64
#define R_ 32
#define K_ 4
#define MLP_ 2048

typedef __bf16 bf16x8 __attribute__((ext_vector_type(8)));
typedef float f32x4 __attribute__((ext_vector_type(4)));
typedef float v2f __attribute__((ext_vector_type(2)));

__device__ __forceinline__ unsigned short f2bf(float f) {
  unsigned int u = __builtin_bit_cast(unsigned int, f);
  return (unsigned short)((u + 0x7FFFu + ((u >> 16) & 1u)) >> 16);
}
__device__ __forceinline__ float bf2f(unsigned short h) {
  return __builtin_bit_cast(float, (unsigned int)h << 16);
}
__device__ __forceinline__ float2 bfp2f(unsigned int u) {
  float2 r;
  r.x = __builtin_bit_cast(float, u << 16);
  r.y = __builtin_bit_cast(float, u & 0xFFFF0000u);
  return r;
}

// async global->LDS, 16B per lane; lds base must be wave-uniform
__device__ __forceinline__ void gload16(const unsigned short* g, unsigned short* l) {
  __builtin_amdgcn_global_load_lds(
      (const __attribute__((address_space(1))) unsigned int*)g,
      (__attribute__((address_space(3))) unsigned int*)l, 16, 0, 0);
}

// DPP add: x + x[perm(lane)] on the VALU pipe (no DS traffic)
template <int CTRL>
__device__ __forceinline__ float dpp_add(float x) {
  int i = __builtin_bit_cast(int, x);
  int j = __builtin_amdgcn_update_dpp(i, i, CTRL, 0xF, 0xF, false);
  return x + __builtin_bit_cast(float, j);
}

// ---------------- all 6 weight transposes in ONE launch ----------------
__global__ __launch_bounds__(256) void transpose_all(
    const float* __restrict__ s0, const float* __restrict__ s1,
    const float* __restrict__ s2, const float* __restrict__ s3,
    const float* __restrict__ s4, const float* __restrict__ s5,
    unsigned short* __restrict__ t0, unsigned short* __restrict__ t1,
    unsigned short* __restrict__ t2, unsigned short* __restrict__ t3,
    unsigned short* __restrict__ t4, unsigned short* __restrict__ t5) {
  __shared__ float t[32][33];
  int bid = blockIdx.x;
  const float* src; unsigned short* dst; int K, N, bx, by;
  if (bid < 1024)      { src = s0; dst = t0; K = 512;  N = 2048; int r = bid;        bx = r & 63; by = r >> 6; }
  else if (bid < 1216) { src = s1; dst = t1; K = 512;  N = 384;  int r = bid - 1024; bx = r % 12; by = r / 12; }
  else if (bid < 1472) { src = s2; dst = t2; K = 1024; N = 256;  int r = bid - 1216; bx = r & 7;  by = r >> 3; }
  else if (bid < 1984) { src = s3; dst = t3; K = 1024; N = 512;  int r = bid - 1472; bx = r & 15; by = r >> 4; }
  else if (bid < 3008) { src = s4; dst = t4; K = 512;  N = 2048; int r = bid - 1984; bx = r & 63; by = r >> 6; }
  else                 { src = s5; dst = t5; K = 2048; N = 512;  int r = bid - 3008; bx = r & 15; by = r >> 4; }
  int nb = bx * 32, kb = by * 32;
  int tx = threadIdx.x & 31, ty = threadIdx.x >> 5;
  for (int r = ty; r < 32; r += 8) t[r][tx] = src[(size_t)(kb + r) * N + nb + tx];
  __syncthreads();
  for (int r = ty; r < 32; r += 8) dst[(size_t)(nb + r) * K + kb + tx] = f2bf(t[tx][r]);
}

// ---------------- cast f32 -> bf16 (for dtw) ----------------
__global__ __launch_bounds__(256) void cast_bf(
    const float* __restrict__ src, unsigned short* __restrict__ dst) {
  int i = (blockIdx.x * 256 + threadIdx.x) * 4;
  float4 v = *(const float4*)(src + i);
  ushort4 o = {f2bf(v.x), f2bf(v.y), f2bf(v.z), f2bf(v.w)};
  *(ushort4*)(dst + i) = o;
}

// ---------------- conv weight transpose: cw (DI,9) -> cwT (9,DI) ----------------
__global__ __launch_bounds__(256) void prep_cw(
    const float* __restrict__ cw, float* __restrict__ cwT) {
  int i = blockIdx.x * 256 + threadIdx.x;
  if (i < DI_ * 9) {
    int d = i / 9, t = i % 9;
    cwT[t * DI_ + d] = cw[i];
  }
}

// ---------------- LayerNorm over 512, wave per row; writes bf16 ----------------
__global__ __launch_bounds__(256) void ln_kernel(
    const float* __restrict__ in0, unsigned short* __restrict__ out0,
    const float* __restrict__ in1, unsigned short* __restrict__ out1,
    const float* __restrict__ w, const float* __restrict__ bb) {
  const float* in = blockIdx.y ? in1 : in0;
  unsigned short* out = blockIdx.y ? out1 : out0;
  int row = blockIdx.x * 4 + (threadIdx.x >> 6);
  int lane = threadIdx.x & 63;
  const float* p = in + (size_t)row * HID_;
  float4 v0 = *(const float4*)(p + lane * 4);
  float4 v1 = *(const float4*)(p + 256 + lane * 4);
  float s = v0.x + v0.y + v0.z + v0.w + v1.x + v1.y + v1.z + v1.w;
  float q = v0.x * v0.x + v0.y * v0.y + v0.z * v0.z + v0.w * v0.w +
            v1.x * v1.x + v1.y * v1.y + v1.z * v1.z + v1.w * v1.w;
  #pragma unroll
  for (int m = 1; m < 64; m <<= 1) { s += __shfl_xor(s, m, 64); q += __shfl_xor(q, m, 64); }
  float mean = s * (1.f / 512.f);
  float var = q * (1.f / 512.f) - mean * mean;
  float rstd = rsqrtf(var + 1e-5f);
  float4 w0 = *(const float4*)(w + lane * 4);
  float4 w1 = *(const float4*)(w + 256 + lane * 4);
  float4 b0 = *(const float4*)(bb + lane * 4);
  float4 b1 = *(const float4*)(bb + 256 + lane * 4);
  unsigned short* o = out + (size_t)row * HID_;
  ushort4 r0, r1;
  r0.x = f2bf((v0.x - mean) * rstd * w0.x + b0.x);
  r0.y = f2bf((v0.y - mean) * rstd * w0.y + b0.y);
  r0.z = f2bf((v0.z - mean) * rstd * w0.z + b0.z);
  r0.w = f2bf((v0.w - mean) * rstd * w0.w + b0.w);
  r1.x = f2bf((v1.x - mean) * rstd * w1.x + b1.x);
  r1.y = f2bf((v1.y - mean) * rstd * w1.y + b1.y);
  r1.z = f2bf((v1.z - mean) * rstd * w1.z + b1.z);
  r1.w = f2bf((v1.w - mean) * rstd * w1.w + b1.w);
  *(ushort4*)(o + lane * 4) = r0;
  *(ushort4*)(o + 256 + lane * 4) = r1;
}

// ---------------- MFMA GEMM 128x128, BK=128, global_load_lds + XOR swizzle ----------------
// LDS rows of 256B (16 x 16B blocks). LDS[r][blk] = G[r][blk ^ (r&7)] via pre-swizzled
// per-lane global source; ds_read applies same XOR -> 2-way bank pattern (free).
#define BM 128
#define BN 128
#define BK 128

template <int EPI, int OUTBF>
__global__ __launch_bounds__(256) void gemm_kernel(
    const unsigned short* __restrict__ A, const unsigned short* __restrict__ BT,
    void* __restrict__ Cv, int M, int N, int K,
    const float* __restrict__ bias, const float* __restrict__ resid) {
  __shared__ __align__(16) unsigned short As[BM * BK];
  __shared__ __align__(16) unsigned short Bs[BN * BK];
  int tid = threadIdx.x;
  int lane = tid & 63, wv = tid >> 6;
  int wm = wv >> 1, wn = wv & 1;
  int nwg = gridDim.x * gridDim.y;
  int flat = blockIdx.y * gridDim.x + blockIdx.x;
  int swz = (flat & 7) * (nwg >> 3) + (flat >> 3);
  int bx = swz % gridDim.x, by = swz / gridDim.x;
  int m0 = by * BM, n0 = bx * BN;
  f32x4 acc[4][4] = {};
  int rowblk = lane >> 4;            // 4 rows per wave pass
  int blk = lane & 15;               // 16B block within 256B row
  int rA = wm * 64 + (lane & 15);
  int rB = wn * 64 + (lane & 15);
  for (int k0 = 0; k0 < K; k0 += BK) {
    __syncthreads();
    #pragma unroll
    for (int it = 0; it < 8; ++it) {
      int r0 = wv * 32 + it * 4;
      int sb = blk ^ ((r0 + rowblk) & 7);
      gload16(A + (size_t)(m0 + r0 + rowblk) * K + k0 + sb * 8, &As[r0 * BK]);
      gload16(BT + (size_t)(n0 + r0 + rowblk) * K + k0 + sb * 8, &Bs[r0 * BK]);
    }
    __syncthreads();
    #pragma unroll
    for (int kx = 0; kx < 4; ++kx) {
      int bidx = (lane >> 4) + kx * 4;
      bf16x8 fa[4], fb[4];
      #pragma unroll
      for (int i = 0; i < 4; ++i) {
        int ra = rA + i * 16;
        int rb = rB + i * 16;
        fa[i] = *(const bf16x8*)&As[ra * BK + ((bidx ^ (ra & 7)) << 3)];
        fb[i] = *(const bf16x8*)&Bs[rb * BK + ((bidx ^ (rb & 7)) << 3)];
      }
      #pragma unroll
      for (int i = 0; i < 4; ++i)
        #pragma unroll
        for (int j = 0; j < 4; ++j)
          acc[i][j] = __builtin_amdgcn_mfma_f32_16x16x32_bf16(fa[i], fb[j], acc[i][j], 0, 0, 0);
    }
  }
  int crow0 = m0 + wm * 64 + (lane >> 4) * 4, ccol0 = n0 + wn * 64 + (lane & 15);
  #pragma unroll
  for (int i = 0; i < 4; ++i) {
    #pragma unroll
    for (int j = 0; j < 4; ++j) {
      int col = ccol0 + j * 16;
      #pragma unroll
      for (int r = 0; r < 4; ++r) {
        int row = crow0 + i * 16 + r;
        float v = acc[i][j][r];
        if (EPI == 1) v += resid[(size_t)row * N + col];
        if (EPI == 2) { v += bias[col]; v = 0.5f * v * (1.f + erff(v * 0.70710678f)); }
        if (EPI == 3) v += bias[col] + resid[(size_t)row * N + col];
        if (OUTBF) ((unsigned short*)Cv)[(size_t)row * N + col] = f2bf(v);
        else       ((float*)Cv)[(size_t)row * N + col] = v;
      }
    }
  }
}

// ---------------- MFMA GEMM 64x128, BK=128, global_load_lds + XOR swizzle ----------------
template <int EPI, int OUTBF>
__global__ __launch_bounds__(256) void gemm64_kernel(
    const unsigned short* __restrict__ A, const unsigned short* __restrict__ BT,
    void* __restrict__ Cv, int M, int N, int K,
    const float* __restrict__ bias, const float* __restrict__ resid) {
  __shared__ __align__(16) unsigned short As[64 * BK];
  __shared__ __align__(16) unsigned short Bs[128 * BK];
  int tid = threadIdx.x;
  int lane = tid & 63, wv = tid >> 6;
  int wm = wv >> 1, wn = wv & 1;
  int nwg = gridDim.x * gridDim.y;
  int flat = blockIdx.y * gridDim.x + blockIdx.x;
  int swz = (flat & 7) * (nwg >> 3) + (flat >> 3);
  int bx = swz % gridDim.x, by = swz / gridDim.x;
  int m0 = by * 64, n0 = bx * BN;
  f32x4 acc[2][4] = {};
  int rowblk = lane >> 4;
  int blk = lane & 15;
  int rA = wm * 32 + (lane & 15);
  int rB = wn * 64 + (lane & 15);
  for (int k0 = 0; k0 < K; k0 += BK) {
    __syncthreads();
    #pragma unroll
    for (int it = 0; it < 4; ++it) {
      int r0 = wv * 16 + it * 4;
      int sb = blk ^ ((r0 + rowblk) & 7);
      gload16(A + (size_t)(m0 + r0 + rowblk) * K + k0 + sb * 8, &As[r0 * BK]);
    }
    #pragma unroll
    for (int it = 0; it < 8; ++it) {
      int r0 = wv * 32 + it * 4;
      int sb = blk ^ ((r0 + rowblk) & 7);
      gload16(BT + (size_t)(n0 + r0 + rowblk) * K + k0 + sb * 8, &Bs[r0 * BK]);
    }
    __syncthreads();
    #pragma unroll
    for (int kx = 0; kx < 4; ++kx) {
      int bidx = (lane >> 4) + kx * 4;
      bf16x8 fa[2], fb[4];
      #pragma unroll
      for (int i = 0; i < 2; ++i) {
        int ra = rA + i * 16;
        fa[i] = *(const bf16x8*)&As[ra * BK + ((bidx ^ (ra & 7)) << 3)];
      }
      #pragma unroll
      for (int j = 0; j < 4; ++j) {
        int rb = rB + j * 16;
        fb[j] = *(const bf16x8*)&Bs[rb * BK + ((bidx ^ (rb & 7)) << 3)];
      }
      #pragma unroll
      for (int i = 0; i < 2; ++i)
        #pragma unroll
        for (int j = 0; j < 4; ++j)
          acc[i][j] = __builtin_amdgcn_mfma_f32_16x16x32_bf16(fa[i], fb[j], acc[i][j], 0, 0, 0);
    }
  }
  int crow0 = m0 + wm * 32 + (lane >> 4) * 4, ccol0 = n0 + wn * 64 + (lane & 15);
  #pragma unroll
  for (int i = 0; i < 2; ++i) {
    #pragma unroll
    for (int j = 0; j < 4; ++j) {
      int col = ccol0 + j * 16;
      #pragma unroll
      for (int r = 0; r < 4; ++r) {
        int row = crow0 + i * 16 + r;
        float v = acc[i][j][r];
        if (EPI == 1) v += resid[(size_t)row * N + col];
        if (EPI == 2) { v += bias[col]; v = 0.5f * v * (1.f + erff(v * 0.70710678f)); }
        if (EPI == 3) v += bias[col] + resid[(size_t)row * N + col];
        if (OUTBF) ((unsigned short*)Cv)[(size_t)row * N + col] = f2bf(v);
        else       ((float*)Cv)[(size_t)row * N + col] = v;
      }
    }
  }
}

// ---------------- delta GEMM: softplus(spRank @ dtw^T + dtb) -> bf16 ----------------
__global__ __launch_bounds__(256) void dtgemm_kernel(
    const unsigned short* __restrict__ sp, const unsigned short* __restrict__ dtwB,
    const float* __restrict__ dtb, unsigned short* __restrict__ delta) {
  int kq = blockIdx.z;
  int m0 = blockIdx.y * 64, n0 = blockIdx.x * 128;
  __shared__ __align__(16) unsigned short As[64 * 32];
  __shared__ __align__(16) unsigned short Bs[128 * 32];
  int tid = threadIdx.x, lane = tid & 63, wv = tid >> 6;
  int wm = wv >> 1, wn = wv & 1;
  {
    int r = tid >> 2, c = (tid & 3) * 8;
    *(uint4*)&As[r * 32 + c] = *(const uint4*)(sp + (size_t)(m0 + r) * 384 + kq * 32 + c);
  }
  {
    int r = tid >> 1, c = (tid & 1) * 16;
    const unsigned short* p = dtwB + (size_t)(kq * DI_ + n0 + r) * 32 + c;
    *(uint4*)&Bs[r * 32 + c] = *(const uint4*)(p);
    *(uint4*)&Bs[r * 32 + c + 8] = *(const uint4*)(p + 8);
  }
  __syncthreads();
  int kk = (lane >> 4) * 8;
  int rA = wm * 32 + (lane & 15);
  int rB = wn * 64 + (lane & 15);
  f32x4 acc[2][4] = {};
  bf16x8 fa[2], fb[4];
  #pragma unroll
  for (int i = 0; i < 2; ++i) fa[i] = *(const bf16x8*)&As[(rA + i * 16) * 32 + kk];
  #pragma unroll
  for (int j = 0; j < 4; ++j) fb[j] = *(const bf16x8*)&Bs[(rB + j * 16) * 32 + kk];
  #pragma unroll
  for (int i = 0; i < 2; ++i)
    #pragma unroll
    for (int j = 0; j < 4; ++j)
      acc[i][j] = __builtin_amdgcn_mfma_f32_16x16x32_bf16(fa[i], fb[j], acc[i][j], 0, 0, 0);
  int crow0 = m0 + wm * 32 + (lane >> 4) * 4, ccol0 = n0 + wn * 64 + (lane & 15);
  #pragma unroll
  for (int i = 0; i < 2; ++i) {
    #pragma unroll
    for (int j = 0; j < 4; ++j) {
      int col = ccol0 + j * 16;
      float bias = dtb[kq * DI_ + col];
      #pragma unroll
      for (int r = 0; r < 4; ++r) {
        int row = crow0 + i * 16 + r;
        float v = acc[i][j][r] + bias;
        v = (v > 15.f) ? v : log1pf(__expf(v));
        int bb = row >> 10, l = row & 1023;
        delta[(((size_t)(bb * 4 + kq)) << 20) + ((size_t)l << 10) + col] = f2bf(v);
      }
    }
  }
}

// ---------------- depthwise 3x3 conv + bias + SiLU; vectorized 8 d/thread ----------------
__global__ __launch_bounds__(256) void conv_kernel(
    const unsigned short* __restrict__ xz, const float* __restrict__ cwT,
    const float* __restrict__ cb, unsigned short* __restrict__ xa) {
  int idx = blockIdx.x * 256 + threadIdx.x;
  int d0 = (idx & 127) * 8;
  int l = (idx >> 7) & (L_ - 1);
  int b = idx >> 17;
  int hh = l >> 5, ww = l & 31;
  float acc[8];
  {
    float4 c0 = *(const float4*)(cb + d0);
    float4 c1 = *(const float4*)(cb + d0 + 4);
    acc[0] = c0.x; acc[1] = c0.y; acc[2] = c0.z; acc[3] = c0.w;
    acc[4] = c1.x; acc[5] = c1.y; acc[6] = c1.z; acc[7] = c1.w;
  }
  #pragma unroll
  for (int dh = -1; dh <= 1; ++dh) {
    int y = hh + dh;
    if ((unsigned)y >= 32u) continue;
    #pragma unroll
    for (int dw = -1; dw <= 1; ++dw) {
      int x = ww + dw;
      if ((unsigned)x >= 32u) continue;
      int tap = (dh + 1) * 3 + (dw + 1);
      uint4 v = *(const uint4*)(xz + ((size_t)b * L_ + y * 32 + x) * (2 * DI_) + d0);
      float4 w0 = *(const float4*)(cwT + tap * DI_ + d0);
      float4 w1 = *(const float4*)(cwT + tap * DI_ + d0 + 4);
      unsigned int wd[4] = {v.x, v.y, v.z, v.w};
      float xv[8];
      #pragma unroll
      for (int t = 0; t < 4; ++t) {
        xv[t * 2 + 0] = __builtin_bit_cast(float, wd[t] << 16);
        xv[t * 2 + 1] = __builtin_bit_cast(float, wd[t] & 0xFFFF0000u);
      }
      acc[0] = fmaf(xv[0], w0.x, acc[0]);
      acc[1] = fmaf(xv[1], w0.y, acc[1]);
      acc[2] = fmaf(xv[2], w0.z, acc[2]);
      acc[3] = fmaf(xv[3], w0.w, acc[3]);
      acc[4] = fmaf(xv[4], w1.x, acc[4]);
      acc[5] = fmaf(xv[5], w1.y, acc[5]);
      acc[6] = fmaf(xv[6], w1.z, acc[6]);
      acc[7] = fmaf(xv[7], w1.w, acc[7]);
    }
  }
  uint4 o;
  float s0 = acc[0] / (1.f + __expf(-acc[0]));
  float s1 = acc[1] / (1.f + __expf(-acc[1]));
  float s2 = acc[2] / (1.f + __expf(-acc[2]));
  float s3 = acc[3] / (1.f + __expf(-acc[3]));
  float s4 = acc[4] / (1.f + __expf(-acc[4]));
  float s5 = acc[5] / (1.f + __expf(-acc[5]));
  float s6 = acc[6] / (1.f + __expf(-acc[6]));
  float s7 = acc[7] / (1.f + __expf(-acc[7]));
  o.x = (unsigned int)f2bf(s0) | ((unsigned int)f2bf(s1) << 16);
  o.y = (unsigned int)f2bf(s2) | ((unsigned int)f2bf(s3) << 16);
  o.z = (unsigned int)f2bf(s4) | ((unsigned int)f2bf(s5) << 16);
  o.w = (unsigned int)f2bf(s6) | ((unsigned int)f2bf(s7) << 16);
  *(uint4*)(xa + ((size_t)b * L_ + l) * DI_ + d0) = o;
}

// ---------------- selective scan: r11 structure (f32 LDS B/C, quad-partial reduce) ----------------
#define CH 16
#define NCH (L_ / CH)
#define DLP 36
#define YQP 6
__global__ __launch_bounds__(512) void scan_kernel(
    unsigned short* __restrict__ ybuf, const unsigned short* __restrict__ xa,
    const unsigned short* __restrict__ sp, const unsigned short* __restrict__ Cs,
    const unsigned short* __restrict__ dltb,
    const float* __restrict__ A_logs, const float* __restrict__ Ds) {
  int dblk = blockIdx.x;
  int k = blockIdx.y, b = blockIdx.z;
  int tid = threadIdx.x, lane = tid & 63, wv = tid >> 6;
  int dg = lane >> 4, ng = lane & 15;
  int qp = (lane >> 2) & 3;
  int wd = wv * 4 + dg;
  int gd = k * DI_ + dblk * 32 + wd;
  v2f a2p[2], h2[2];
  #pragma unroll
  for (int j = 0; j < 2; ++j) {
    a2p[j].x = -__expf(A_logs[(size_t)gd * N_ + ng * 4 + 2 * j]) * 1.44269504f;
    a2p[j].y = -__expf(A_logs[(size_t)gd * N_ + ng * 4 + 2 * j + 1]) * 1.44269504f;
    h2[j].x = 0.f; h2[j].y = 0.f;
  }

  __shared__ float Bsh[2][CH][64];
  __shared__ float Csh[2][CH][64];
  __shared__ float DLU[2][32][DLP];
  __shared__ float yq[CH][32][YQP];
  __shared__ float dsh[32];

  const size_t spB = (size_t)b * L_ * 384 + 128 + k * 64;
  const size_t csB = (size_t)b * L_ * 256 + k * 64;
  const size_t dlB = ((size_t)(b * 4 + k) * L_) * DI_ + dblk * 32;
  const size_t xaB = (size_t)b * L_ * DI_ + dblk * 32;

  if (tid < 32) dsh[tid] = Ds[k * DI_ + dblk * 32 + tid];

  int liS = tid >> 5, js = tid & 31;
  int liE = tid >> 5, dd = tid & 31;
  auto posf = [&](int l) {
    int lr = 1023 - l;
    return (k == 0) ? l
         : (k == 1) ? ((l & 31) * 32 + (l >> 5))
         : (k == 2) ? lr
                    : ((lr & 31) * 32 + (lr >> 5));
  };

  {
    float2 fB = bfp2f(*(const unsigned int*)(sp + spB + (size_t)liS * 384 + js * 2));
    float2 fC = bfp2f(*(const unsigned int*)(Cs + csB + (size_t)liS * 256 + js * 2));
    *(float2*)&Bsh[0][liS][js * 2] = fB;
    *(float2*)&Csh[0][liS][js * 2] = fC;
    float2 p;
    p.x = bf2f(dltb[dlB + (size_t)liS * DI_ + js]);
    p.y = bf2f(xa[xaB + (size_t)posf(liS) * DI_ + js]);
    *(float2*)&DLU[0][js][liS * 2] = p;
  }
  __syncthreads();

  int cur = 0;
  for (int c = 0; c < NCH; ++c) {
    unsigned int pB, pC;
    unsigned short pD, pU;
    if (c < NCH - 1) {
      int lb = (c + 1) * CH + liS;
      pB = *(const unsigned int*)(sp + spB + (size_t)lb * 384 + js * 2);
      pC = *(const unsigned int*)(Cs + csB + (size_t)lb * 256 + js * 2);
      pD = dltb[dlB + (size_t)lb * DI_ + js];
      pU = xa[xaB + (size_t)posf(lb) * DI_ + js];
    }
    #pragma unroll
    for (int li2 = 0; li2 < CH; li2 += 2) {
      f32x4 duq = *(const f32x4*)&DLU[cur][wd][li2 * 2];
      #pragma unroll
      for (int s = 0; s < 2; ++s) {
        int li = li2 + s;
        float dlt = s ? duq[2] : duq[0];
        float u   = s ? duq[3] : duq[1];
        float du = dlt * u;
        f32x4 bq = *(const f32x4*)&Bsh[cur][li][ng * 4];
        f32x4 cq = *(const f32x4*)&Csh[cur][li][ng * 4];
        v2f b01 = __builtin_shufflevector(bq, bq, 0, 1);
        v2f b23 = __builtin_shufflevector(bq, bq, 2, 3);
        v2f c01 = __builtin_shufflevector(cq, cq, 0, 1);
        v2f c23 = __builtin_shufflevector(cq, cq, 2, 3);
        v2f dlt2; dlt2.x = dlt; dlt2.y = dlt;
        v2f du2;  du2.x = du;  du2.y = du;
        v2f arg0 = dlt2 * a2p[0];
        v2f arg1 = dlt2 * a2p[1];
        v2f e0, e1;
        e0.x = __builtin_amdgcn_exp2f(arg0.x);
        e0.y = __builtin_amdgcn_exp2f(arg0.y);
        e1.x = __builtin_amdgcn_exp2f(arg1.x);
        e1.y = __builtin_amdgcn_exp2f(arg1.y);
        h2[0] = e0 * h2[0] + du2 * b01;
        h2[1] = e1 * h2[1] + du2 * b23;
        v2f yv = h2[0] * c01 + h2[1] * c23;
        float yp = yv.x + yv.y;
        yp = dpp_add<0xB1>(yp);
        yp = dpp_add<0x4E>(yp);
        yq[li][wd][qp] = yp;
      }
    }
    __syncthreads();
    {
      float2 q01 = *(const float2*)&yq[liE][dd][0];
      float2 q23 = *(const float2*)&yq[liE][dd][2];
      float y = (q01.x + q01.y) + (q23.x + q23.y);
      float u = DLU[cur][dd][liE * 2 + 1];
      y = fmaf(u, dsh[dd], y);
      ybuf[dlB + (size_t)(c * CH + liE) * DI_ + dd] = f2bf(y);
    }
    if (c < NCH - 1) {
      int nxt = cur ^ 1;
      *(float2*)&Bsh[nxt][liS][js * 2] = bfp2f(pB);
      *(float2*)&Csh[nxt][liS][js * 2] = bfp2f(pC);
      float2 p; p.x = bf2f(pD); p.y = bf2f(pU);
      *(float2*)&DLU[nxt][js][liS * 2] = p;
    }
    __syncthreads();
    cur ^= 1;
  }
}

// ---------------- fuse: ygz = (sum_k yk) * z  (yk bf16, z bf16) -> bf16 ----------------
__global__ __launch_bounds__(256) void fuse_ygz(
    const unsigned short* __restrict__ yk, const unsigned short* __restrict__ xz,
    unsigned short* __restrict__ ygz) {
  size_t i = ((size_t)blockIdx.x * 256 + threadIdx.x) * 8;
  size_t b = i >> 20, ld = i & ((1u << 20) - 1);
  float acc[8] = {};
  #pragma unroll
  for (int k = 0; k < 4; ++k) {
    uint4 v = *(const uint4*)(yk + ((size_t)(b * 4 + k) << 20) + ld);
    unsigned int w[4] = {v.x, v.y, v.z, v.w};
    #pragma unroll
    for (int t = 0; t < 4; ++t) {
      acc[t * 2 + 0] += __builtin_bit_cast(float, w[t] << 16);
      acc[t * 2 + 1] += __builtin_bit_cast(float, w[t] & 0xFFFF0000u);
    }
  }
  uint4 zv = *(const uint4*)(xz + (i >> 10) * (2 * DI_) + DI_ + (i & (DI_ - 1)));
  unsigned int zw[4] = {zv.x, zv.y, zv.z, zv.w};
  float z[8];
  #pragma unroll
  for (int t = 0; t < 4; ++t) {
    z[t * 2 + 0] = __builtin_bit_cast(float, zw[t] << 16);
    z[t * 2 + 1] = __builtin_bit_cast(float, zw[t] & 0xFFFF0000u);
  }
  uint4 o;
  o.x = (unsigned int)f2bf(acc[0] * z[0]) | ((unsigned int)f2bf(acc[1] * z[1]) << 16);
  o.y = (unsigned int)f2bf(acc[2] * z[2]) | ((unsigned int)f2bf(acc[3] * z[3]) << 16);
  o.z = (unsigned int)f2bf(acc[4] * z[4]) | ((unsigned int)f2bf(acc[5] * z[5]) << 16);
  o.w = (unsigned int)f2bf(acc[6] * z[6]) | ((unsigned int)f2bf(acc[7] * z[7]) << 16);
  *(uint4*)(ygz + i) = o;
}

// ---------------- host ----------------
extern "C" void kernel_launch(void* const* d_in, const int* in_sizes, int n_in,
                              void* d_out, int out_size, void* d_ws, size_t ws_size,
                              hipStream_t stream) {
  (void)in_sizes; (void)n_in; (void)out_size; (void)ws_size;
  const float* content   = (const float*)d_in[0];
  const float* style     = (const float*)d_in[1];
  const float* norm1_w   = (const float*)d_in[2];
  const float* norm1_b   = (const float*)d_in[3];
  const float* in_proj_w = (const float*)d_in[4];
  const float* conv_w    = (const float*)d_in[5];
  const float* conv_b    = (const float*)d_in[6];
  const float* style_proj_w   = (const float*)d_in[7];
  const float* content_proj_w = (const float*)d_in[8];
  const float* dtw       = (const float*)d_in[9];
  const float* dtb       = (const float*)d_in[10];
  const float* A_logs    = (const float*)d_in[11];
  const float* Ds        = (const float*)d_in[12];
  const float* out_proj_w = (const float*)d_in[13];
  const float* norm2_w   = (const float*)d_in[14];
  const float* norm2_b   = (const float*)d_in[15];
  const float* mlp_w1    = (const float*)d_in[16];
  const float* mlp_b1    = (const float*)d_in[17];
  const float* mlp_w2    = (const float*)d_in[18];
  const float* mlp_b2    = (const float*)d_in[19];
  float* out = (float*)d_out;

  float* ws = (float*)d_ws;
  const size_t ROWS = (size_t)B_ * L_;
  const size_t SCAN_ELEMS = (size_t)B_ * K_ * L_ * DI_;
  size_t o = 0;
  unsigned short* cn  = (unsigned short*)(ws + o); o += ROWS * HID_ / 2;
  unsigned short* sn  = (unsigned short*)(ws + o); o += ROWS * HID_ / 2;
  unsigned short* xn  = (unsigned short*)(ws + o); o += ROWS * HID_ / 2;
  unsigned short* xz  = (unsigned short*)(ws + o); o += ROWS * 2 * DI_ / 2;
  unsigned short* sp  = (unsigned short*)(ws + o); o += ROWS * 384 / 2;
  unsigned short* xa  = (unsigned short*)(ws + o); o += ROWS * DI_ / 2;
  unsigned short* csb = (unsigned short*)(ws + o); o += ROWS * 256 / 2;
  float* x1    = ws + o; o += ROWS * HID_;
  unsigned short* dltb = (unsigned short*)(ws + o); o += SCAN_ELEMS / 2;
  unsigned short* ybuf = (unsigned short*)(ws + o); o += SCAN_ELEMS / 2;
  unsigned short* ygz  = (unsigned short*)(ws + o); o += ROWS * DI_ / 2;
  unsigned short* wt = (unsigned short*)(ws + o);
  unsigned short* inpT = wt;
  unsigned short* styT = inpT + 2048 * 512;
  unsigned short* conT = styT + 384 * 512;
  unsigned short* outT = conT + 256 * 1024;
  unsigned short* w1T  = outT + 512 * 1024;
  unsigned short* w2T  = w1T + 2048 * 512;
  unsigned short* dtwB = w2T + 512 * 2048;               // (K*DI,32) bf16
  float* cwT = (float*)(dtwB + (size_t)K_ * DI_ * R_);   // (9,DI) f32
  unsigned short* hmid = ybuf;

  transpose_all<<<4032, 256, 0, stream>>>(
      in_proj_w, style_proj_w, content_proj_w, out_proj_w, mlp_w1, mlp_w2,
      inpT, styT, conT, outT, w1T, w2T);
  cast_bf<<<(K_ * DI_ * R_) / 1024, 256, 0, stream>>>(dtw, dtwB);
  prep_cw<<<36, 256, 0, stream>>>(conv_w, cwT);

  ln_kernel<<<dim3(ROWS / 4, 2), 256, 0, stream>>>(content, cn, style, sn, norm1_w, norm1_b);

  gemm_kernel<0, 1><<<dim3(2048 / BN, ROWS / BM), 256, 0, stream>>>(
      cn, inpT, xz, ROWS, 2048, 512, nullptr, nullptr);
  gemm64_kernel<0, 1><<<dim3(384 / BN, ROWS / 64), 256, 0, stream>>>(
      sn, styT, sp, ROWS, 384, 512, nullptr, nullptr);
  conv_kernel<<<(ROWS * DI_) / (256 * 8), 256, 0, stream>>>(xz, cwT, conv_b, xa);
  gemm64_kernel<0, 1><<<dim3(256 / BN, ROWS / 64), 256, 0, stream>>>(
      xa, conT, csb, ROWS, 256, 1024, nullptr, nullptr);
  dtgemm_kernel<<<dim3(DI_ / 128, ROWS / 64, K_), 256, 0, stream>>>(sp, dtwB, dtb, dltb);
  scan_kernel<<<dim3(DI_ / 32, K_, B_), 512, 0, stream>>>(
      ybuf, xa, sp, csb, dltb, A_logs, Ds);
  fuse_ygz<<<(ROWS * DI_) / (256 * 8), 256, 0, stream>>>(ybuf, xz, ygz);
  gemm64_kernel<1, 0><<<dim3(512 / BN, ROWS / 64), 256, 0, stream>>>(
      ygz, outT, x1, ROWS, 512, 1024, nullptr, content);
  ln_kernel<<<dim3(ROWS / 4, 1), 256, 0, stream>>>(x1, xn, nullptr, nullptr, norm2_w, norm2_b);
  gemm_kernel<2, 1><<<dim3(2048 / BN, ROWS / BM), 256, 0, stream>>>(
      xn, w1T, hmid, ROWS, 2048, 512, mlp_b1, nullptr);
  gemm64_kernel<3, 0><<<dim3(512 / BN, ROWS / 64), 256, 0, stream>>>(
      hmid, w2T, out, ROWS, 512, 2048, mlp_b2, x1);
}